// Round 4
// baseline (279.418 us; speedup 1.0000x reference)
//
#include <hip/hip_runtime.h>
#include <math.h>

// ---------------------------------------------------------------------------
// LightweightEncoder, round 4: LDS-vectorized thin bands, in-block sigma,
// 5 launches.
//  k_band_l0  : per 64x16 x_init band: ctx L0 (h0), sample conv (x, with
//               per-block lane-parallel sigma), pool1, pool2. Block 0 zeroes acc.
//  k_band_ctx : band ctx conv (L1,L2,L3), BN+ReLU pre-applied at staging.
//  k_final    : select + soft VQ + counts + 3 histograms (per-wave LDS
//               slices) + last-block finalize.
// LDS band layout: 17 rows x stride 72 floats, halo-inclusive: LDS col j <->
// global col gc0-4+j (reads use j=3..67). 16B-aligned rows, uniform float4
// staging, <=2-way bank aliasing everywhere.
// ---------------------------------------------------------------------------

#define SENT -1e30f      // OOB sentinel: relu(inv*SENT+bb)==0 (pad-after-bnrelu)
#define BSTR 72
#define BCH  (17 * BSTR)

__device__ __forceinline__ float featf(float h) { return 0.5f * (tanhf(h) + 1.0f); }

// stage raw 17-row halo-inclusive band (289 float4 tiles), uniform mapping
__device__ __forceinline__ void stage_raw(const float* __restrict__ base,
                                          float* __restrict__ L,
                                          int gr0, int gc0, int S, int t) {
    for (int idx = t; idx < 289; idx += 256) {
        int lr = idx / 17;
        int s  = idx - lr * 17;
        int gr = gr0 + lr;
        int gc = gc0 - 4 + 4 * s;
        float4 v;
        if (gr >= 0 && gr < S && gc >= 0)
            v = *(const float4*)(base + (size_t)gr * S + gc);
        else { v.x = SENT; v.y = SENT; v.z = SENT; v.w = SENT; }
        *(float4*)&L[lr * BSTR + 4 * s] = v;   // (4s)*4B -> 16B aligned
    }
}

// stage with BN+ReLU applied (ctx-only layers); OOB -> 0 automatically
__device__ __forceinline__ void stage_bn(const float* __restrict__ base,
                                         float* __restrict__ L,
                                         int gr0, int gc0, int S, int t,
                                         float inv, float bb) {
    for (int idx = t; idx < 289; idx += 256) {
        int lr = idx / 17;
        int s  = idx - lr * 17;
        int gr = gr0 + lr;
        int gc = gc0 - 4 + 4 * s;
        float4 v;
        if (gr >= 0 && gr < S && gc >= 0)
            v = *(const float4*)(base + (size_t)gr * S + gc);
        else { v.x = SENT; v.y = SENT; v.z = SENT; v.w = SENT; }
        v.x = fmaxf(fmaf(inv, v.x, bb), 0.0f);
        v.y = fmaxf(fmaf(inv, v.y, bb), 0.0f);
        v.z = fmaxf(fmaf(inv, v.z, bb), 0.0f);
        v.w = fmaxf(fmaf(inv, v.w, bb), 0.0f);
        *(float4*)&L[lr * BSTR + 4 * s] = v;
    }
}

// ---------------------------------------------------------------------------
// K0: L0 band kernel. grid = 8 b * 64 bands * 16 tiles = 8192, block 256.
// ---------------------------------------------------------------------------
__global__ __launch_bounds__(256) void k_band_l0(
    const float* __restrict__ xin,
    const float* __restrict__ sw_g, const float* __restrict__ sb,
    const float* __restrict__ ctxw, const float* __restrict__ ctxb,
    const float* __restrict__ bng, const float* __restrict__ bnb,
    const float* __restrict__ p1w, const float* __restrict__ p1b,
    const float* __restrict__ p2w, const float* __restrict__ p2b,
    float* __restrict__ outX, float* __restrict__ outH0,
    float* __restrict__ outP1, float* __restrict__ outP2,
    int* __restrict__ acc)
{
    __shared__ float sx[3 * BCH];
    __shared__ float sxo[3][4][16];
    __shared__ float sp1[3][2][8];

    int t = threadIdx.x, bid = blockIdx.x;
    int tileX = bid & 15, bandY = (bid >> 4) & 63, b = bid >> 10;

    if (bid == 0 && t < 12) acc[t] = 0;    // hist[8] + counts[3] + k_final counter

    int gr0 = bandY * 16 - 1;
    int gc0 = tileX * 64;
    for (int c = 0; c < 3; c++)
        stage_raw(xin + ((size_t)(b * 3 + c) << 20), &sx[c * BCH], gr0, gc0, 1024, t);
    __syncthreads();

    // ---- ctx L0: 32x8 outputs, 1/thread; BN+ReLU applied at read ----
    {
        int ox = t & 31, oy = t >> 5;
        float a0 = ctxb[0], a1 = ctxb[1], a2 = ctxb[2];
        #pragma unroll
        for (int c = 0; c < 3; c++) {
            float inv = bng[c] / sqrtf(1.001f), bb = bnb[c];
            const float* Lc = &sx[c * BCH];
            #pragma unroll
            for (int kh = 0; kh < 3; kh++) {
                const float* Lr = Lc + (2 * oy + kh) * BSTR + 2 * ox + 2;
                float2 u = *(const float2*)Lr;         // cols 2ox-2, 2ox-1
                float2 w2 = *(const float2*)(Lr + 2);  // cols 2ox,   2ox+1
                float t0 = fmaxf(fmaf(inv, u.y,  bb), 0.0f);
                float t1 = fmaxf(fmaf(inv, w2.x, bb), 0.0f);
                float t2 = fmaxf(fmaf(inv, w2.y, bb), 0.0f);
                int wi = c * 9 + kh * 3;
                a0 = fmaf(ctxw[wi], t0, a0); a0 = fmaf(ctxw[wi + 1], t1, a0); a0 = fmaf(ctxw[wi + 2], t2, a0);
                a1 = fmaf(ctxw[27 + wi], t0, a1); a1 = fmaf(ctxw[28 + wi], t1, a1); a1 = fmaf(ctxw[29 + wi], t2, a1);
                a2 = fmaf(ctxw[54 + wi], t0, a2); a2 = fmaf(ctxw[55 + wi], t1, a2); a2 = fmaf(ctxw[56 + wi], t2, a2);
            }
        }
        size_t o = ((size_t)(b * 3)) * 262144 + (size_t)(bandY * 8 + oy) * 512 + tileX * 32 + ox;
        outH0[o] = a0; outH0[o + 262144] = a1; outH0[o + 524288] = a2;
    }

    // ---- wave 0: sigma (lane-parallel Gram + lane-0 eig) + sample conv ----
    if (t < 64) {
        float p00 = 0.f, p01 = 0.f, p02 = 0.f, p11 = 0.f, p12 = 0.f, p22 = 0.f;
        if (t < 48) {
            float a0 = sw_g[t], a1 = sw_g[48 + t], a2 = sw_g[96 + t];
            p00 = a0 * a0; p01 = a0 * a1; p02 = a0 * a2;
            p11 = a1 * a1; p12 = a1 * a2; p22 = a2 * a2;
        }
        #pragma unroll
        for (int off = 32; off > 0; off >>= 1) {
            p00 += __shfl_down(p00, off); p01 += __shfl_down(p01, off);
            p02 += __shfl_down(p02, off); p11 += __shfl_down(p11, off);
            p12 += __shfl_down(p12, off); p22 += __shfl_down(p22, off);
        }
        float inv_sigma = 0.0f;
        if (t == 0) {
            // float closed-form largest eigenvalue of Gram, double Newton polish
            float q = (p00 + p11 + p22) * (1.0f / 3.0f);
            float pp1 = p01 * p01 + p02 * p02 + p12 * p12;
            float pp2 = (p00 - q) * (p00 - q) + (p11 - q) * (p11 - q)
                      + (p22 - q) * (p22 - q) + 2.0f * pp1;
            float lam;
            if (pp2 < 1e-30f) lam = q;
            else {
                float pr = sqrtf(pp2 / 6.0f);
                float B00 = (p00 - q) / pr, B01 = p01 / pr, B02 = p02 / pr;
                float B11 = (p11 - q) / pr, B12 = p12 / pr, B22 = (p22 - q) / pr;
                float detB = B00 * (B11 * B22 - B12 * B12)
                           - B01 * (B01 * B22 - B12 * B02)
                           + B02 * (B01 * B12 - B11 * B02);
                float r = fminf(1.0f, fmaxf(-1.0f, 0.5f * detB));
                lam = q + 2.0f * pr * cosf(acosf(r) * (1.0f / 3.0f));
            }
            double G00 = p00, G01 = p01, G02 = p02, G11 = p11, G12 = p12, G22 = p22;
            double c2 = G00 + G11 + G22;
            double c1 = G00 * G11 - G01 * G01 + G00 * G22 - G02 * G02 + G11 * G22 - G12 * G12;
            double c0 = G00 * (G11 * G22 - G12 * G12) - G01 * (G01 * G22 - G12 * G02)
                      + G02 * (G01 * G12 - G11 * G02);
            double L = (double)lam;
            #pragma unroll
            for (int it = 0; it < 2; it++) {
                double pv = ((L - c2) * L + c1) * L - c0;
                double dv = (3.0 * L - 2.0 * c2) * L + c1;
                L -= pv / dv;
            }
            inv_sigma = (float)(1.0 / sqrt(L));
        }
        inv_sigma = __shfl(inv_sigma, 0);

        int xl = t & 15, yl = t >> 4;
        float s0 = 0.f, s1 = 0.f, s2 = 0.f;
        #pragma unroll
        for (int c = 0; c < 3; c++) {
            const float* Lc = &sx[c * BCH];
            #pragma unroll
            for (int kh = 0; kh < 4; kh++) {
                float4 v = *(const float4*)&Lc[(1 + 4 * yl + kh) * BSTR + 4 + 4 * xl];
                const float* w0 = &sw_g[(0 * 3 + c) * 16 + kh * 4];
                const float* w1 = &sw_g[(1 * 3 + c) * 16 + kh * 4];
                const float* w2 = &sw_g[(2 * 3 + c) * 16 + kh * 4];
                s0 += w0[0] * v.x + w0[1] * v.y + w0[2] * v.z + w0[3] * v.w;
                s1 += w1[0] * v.x + w1[1] * v.y + w1[2] * v.z + w1[3] * v.w;
                s2 += w2[0] * v.x + w2[1] * v.y + w2[2] * v.z + w2[3] * v.w;
            }
        }
        float x0 = fmaf(s0, inv_sigma, sb[0]);
        float x1 = fmaf(s1, inv_sigma, sb[1]);
        float x2 = fmaf(s2, inv_sigma, sb[2]);
        size_t o = ((size_t)(b * 3)) * 65536 + (size_t)(bandY * 4 + yl) * 256 + tileX * 16 + xl;
        outX[o] = x0; outX[o + 65536] = x1; outX[o + 131072] = x2;
        sxo[0][yl][xl] = x0; sxo[1][yl][xl] = x1; sxo[2][yl][xl] = x2;
    }
    __syncthreads();

    // ---- pool1: 8x2 outputs on threads 0..15 ----
    if (t < 16) {
        int px = t & 7, py = t >> 3;
        float a0 = p1b[0], a1 = p1b[1], a2 = p1b[2];
        #pragma unroll
        for (int c = 0; c < 3; c++)
            #pragma unroll
            for (int kh = 0; kh < 2; kh++)
                #pragma unroll
                for (int kw = 0; kw < 2; kw++) {
                    float v = sxo[c][2 * py + kh][2 * px + kw];
                    int wi = c * 4 + kh * 2 + kw;
                    a0 = fmaf(p1w[wi], v, a0);
                    a1 = fmaf(p1w[12 + wi], v, a1);
                    a2 = fmaf(p1w[24 + wi], v, a2);
                }
        size_t o = ((size_t)(b * 3)) * 16384 + (size_t)(bandY * 2 + py) * 128 + tileX * 8 + px;
        outP1[o] = a0; outP1[o + 16384] = a1; outP1[o + 32768] = a2;
        sp1[0][py][px] = a0; sp1[1][py][px] = a1; sp1[2][py][px] = a2;
    }
    __syncthreads();

    // ---- pool2: 4x1 outputs on threads 0..3 ----
    if (t < 4) {
        int px = t;
        float a0 = p2b[0], a1 = p2b[1], a2 = p2b[2];
        #pragma unroll
        for (int c = 0; c < 3; c++)
            #pragma unroll
            for (int kh = 0; kh < 2; kh++)
                #pragma unroll
                for (int kw = 0; kw < 2; kw++) {
                    float v = sp1[c][kh][2 * px + kw];
                    int wi = c * 4 + kh * 2 + kw;
                    a0 = fmaf(p2w[wi], v, a0);
                    a1 = fmaf(p2w[12 + wi], v, a1);
                    a2 = fmaf(p2w[24 + wi], v, a2);
                }
        size_t o = ((size_t)(b * 3)) * 4096 + (size_t)bandY * 64 + tileX * 4 + px;
        outP2[o] = a0; outP2[o + 4096] = a1; outP2[o + 8192] = a2;
    }
}

// ---------------------------------------------------------------------------
// K1: band ctx conv (L1..L3); BN+ReLU pre-applied at staging.
// ---------------------------------------------------------------------------
__global__ __launch_bounds__(256) void k_band_ctx(
    const float* __restrict__ in, float* __restrict__ outH, float* __restrict__ outF,
    const float* __restrict__ w, const float* __restrict__ bias,
    const float* __restrict__ bng, const float* __restrict__ bnb,
    int S, int tpxbits, int bandbits)
{
    __shared__ float sx[3 * BCH];
    int t = threadIdx.x, bid = blockIdx.x;
    int tileX = bid & ((1 << tpxbits) - 1);
    int bandY = (bid >> tpxbits) & ((1 << bandbits) - 1);
    int b = bid >> (tpxbits + bandbits);

    int gr0 = bandY * 16 - 1;
    int gc0 = tileX * 64;
    for (int c = 0; c < 3; c++) {
        float inv = bng[c] / sqrtf(1.001f), bb = bnb[c];
        stage_bn(in + (size_t)(b * 3 + c) * S * S, &sx[c * BCH], gr0, gc0, S, t, inv, bb);
    }
    __syncthreads();

    int So = S >> 1;
    size_t os = (size_t)So * So;
    int ox = t & 31, oy = t >> 5;
    float a0 = bias[0], a1 = bias[1], a2 = bias[2];
    #pragma unroll
    for (int c = 0; c < 3; c++) {
        const float* Lc = &sx[c * BCH];
        #pragma unroll
        for (int kh = 0; kh < 3; kh++) {
            const float* Lr = Lc + (2 * oy + kh) * BSTR + 2 * ox + 2;
            float2 u = *(const float2*)Lr;
            float2 w2 = *(const float2*)(Lr + 2);
            float t0 = u.y, t1 = w2.x, t2 = w2.y;
            int wi = c * 9 + kh * 3;
            a0 = fmaf(w[wi], t0, a0); a0 = fmaf(w[wi + 1], t1, a0); a0 = fmaf(w[wi + 2], t2, a0);
            a1 = fmaf(w[27 + wi], t0, a1); a1 = fmaf(w[28 + wi], t1, a1); a1 = fmaf(w[29 + wi], t2, a1);
            a2 = fmaf(w[54 + wi], t0, a2); a2 = fmaf(w[55 + wi], t1, a2); a2 = fmaf(w[56 + wi], t2, a2);
        }
    }
    size_t o = (size_t)(b * 3) * os + (size_t)(bandY * 8 + oy) * So + tileX * 32 + ox;
    if (outH) { outH[o] = a0; outH[o + os] = a1; outH[o + 2 * os] = a2; }
    if (outF) { outF[o] = featf(a0); outF[o + os] = featf(a1); outF[o + 2 * os] = featf(a2); }
}

// ---------------------------------------------------------------------------
// K2: final select + soft VQ + counts + histograms + last-block finalize.
// ---------------------------------------------------------------------------
__device__ __forceinline__ int argmin8(float v, const float* __restrict__ sc) {
    float best = 1e30f; int ki = 0;
    #pragma unroll
    for (int k = 0; k < 8; k++) {
        float df = v - sc[k]; float dk = df * df;
        if (dk < best) { best = dk; ki = k; }
    }
    return ki;
}

__global__ __launch_bounds__(256) void k_final(
    const float* __restrict__ x, const float* __restrict__ f1,
    const float* __restrict__ f2, const float* __restrict__ p1,
    const float* __restrict__ p2, const float* __restrict__ thresh,
    const float* __restrict__ centers, float* __restrict__ out,
    int* __restrict__ acc, float* __restrict__ out2)
{
    __shared__ int sh[4 * 12];              // per-wave slices: hist[8]+counts[3]
    __shared__ bool s_last;
    int t = threadIdx.x;
    int lane = t & 63;
    int* shW = &sh[12 * (t >> 6)];
    if (lane < 12) shW[lane] = 0;
    if (t == 0) s_last = false;
    float sc[8];
    #pragma unroll
    for (int k = 0; k < 8; k++) sc[k] = centers[k];
    __syncthreads();

    float th1 = thresh[0], th2 = thresh[1];
    int gid = blockIdx.x * 256 + t;
    int xc = gid & 255, y = (gid >> 8) & 255, b = gid >> 16;
    int i2 = ((y >> 1) << 7) + (xc >> 1);
    int i4 = ((y >> 2) << 6) + (xc >> 2);
    bool doM1 = ((y & 1) == 0) && ((xc & 1) == 0);
    bool doM2 = ((y & 3) == 0) && ((xc & 3) == 0);
    int c0n = 0, c1n = 0, c2n = 0;

    for (int c = 0; c < 3; c++) {
        int pc = b * 3 + c;
        float f1v = f1[(size_t)pc * 16384 + i2];
        float f2v = f2[(size_t)pc * 4096 + i4];
        float p1v = p1[(size_t)pc * 16384 + i2];
        float p2v = p2[(size_t)pc * 4096 + i4];
        float xv  = x[(size_t)pc * 65536 + (y << 8) + xc];
        bool cond2 = f2v < th2;
        bool cond1 = (!cond2) && (f1v < th1);
        bool cond0 = !(cond1 || cond2);
        float xq = cond2 ? p2v : (cond1 ? p1v : xv);

        float d[8]; float dmin = 1e30f;
        #pragma unroll
        for (int k = 0; k < 8; k++) { float df = xq - sc[k]; d[k] = df * df; dmin = fminf(dmin, d[k]); }
        float se = 0.f, sn = 0.f;
        #pragma unroll
        for (int k = 0; k < 8; k++) { float e = __expf(dmin - d[k]); se += e; sn = fmaf(sc[k], e, sn); }
        out[(size_t)pc * 65536 + (y << 8) + xc] = sn / se;

        c0n += cond0; c1n += cond1; c2n += cond2;

        if (cond0) atomicAdd(&shW[argmin8(xv, sc)], 1);
        if (doM1 && (f2v >= th2) && (f1v < th1)) atomicAdd(&shW[argmin8(p1v, sc)], 1);
        if (doM2 && cond2) atomicAdd(&shW[argmin8(p2v, sc)], 1);
    }
    #pragma unroll
    for (int off = 32; off > 0; off >>= 1) {
        c0n += __shfl_down(c0n, off);
        c1n += __shfl_down(c1n, off);
        c2n += __shfl_down(c2n, off);
    }
    if (lane == 0) { atomicAdd(&shW[8], c0n); atomicAdd(&shW[9], c1n); atomicAdd(&shW[10], c2n); }
    __syncthreads();
    if (t < 11) {
        int v = sh[t] + sh[12 + t] + sh[24 + t] + sh[36 + t];
        if (v) atomicAdd(&acc[t], v);
    }
    __syncthreads();
    if (t == 0) {
        __threadfence();
        unsigned done = atomicAdd((unsigned*)&acc[11], 1u);
        s_last = (done == (unsigned)(gridDim.x - 1));
    }
    __syncthreads();
    if (s_last && t == 0) {
        int av[11];
        #pragma unroll
        for (int k = 0; k < 11; k++) av[k] = atomicAdd(&acc[k], 0);
        float cnt0 = (float)av[8], cnt1 = (float)av[9], cnt2 = (float)av[10];
        float esti = cnt0 + cnt1 * 0.25f + cnt2 * 0.0625f;
        float cr = (1.0f / 16.0f) * esti / (256.0f * 256.0f * 3.0f * 8.0f);
        float cs[8]; float tot = 0.0f;
        #pragma unroll
        for (int k = 0; k < 8; k++) { cs[k] = (float)av[k]; tot += cs[k]; }
        float mean = 0.0f;
        #pragma unroll
        for (int k = 0; k < 8; k++) { cs[k] /= tot; mean += cs[k]; }
        mean *= 0.125f;
        float var = 0.0f;
        #pragma unroll
        for (int k = 0; k < 8; k++) { float df = cs[k] - mean; var += df * df; }
        var *= (1.0f / 7.0f);
        out2[0] = cr;
        out2[1] = sqrtf(var);
    }
}

extern "C" void kernel_launch(void* const* d_in, const int* in_sizes, int n_in,
                              void* d_out, int out_size, void* d_ws, size_t ws_size,
                              hipStream_t stream) {
    const float* x_init   = (const float*)d_in[0];
    const float* thresh   = (const float*)d_in[1];
    const float* sample_w = (const float*)d_in[2];
    const float* sample_b = (const float*)d_in[3];
    const float* centers  = (const float*)d_in[4];
    const float* pool1_w  = (const float*)d_in[5];
    const float* pool1_b  = (const float*)d_in[6];
    const float* pool2_w  = (const float*)d_in[7];
    const float* pool2_b  = (const float*)d_in[8];
    const float* ctx_w    = (const float*)d_in[9];
    const float* ctx_b    = (const float*)d_in[10];
    const float* bn_g     = (const float*)d_in[11];
    const float* bn_b     = (const float*)d_in[12];
    float* out = (float*)d_out;

    float* wsf   = (float*)d_ws;
    int*   acc   = (int*)wsf;                  // acc[0..10] + counter[11]
    float* bufX  = wsf + 256;                  // [8,3,256,256]
    float* bufH0 = bufX  + 1572864;            // [8,3,512,512]
    float* bufH1 = bufH0 + 6291456;            // [8,3,256,256]
    float* bufH2 = bufH1 + 1572864;            // [8,3,128,128]
    float* bufP1 = bufH2 + 393216;             // [8,3,128,128]
    float* bufP2 = bufP1 + 393216;             // [8,3,64,64]
    float* bufF1 = bufP2 + 98304;              // [8,3,128,128]
    float* bufF2 = bufF1 + 393216;             // [8,3,64,64]

    k_band_l0<<<8192, 256, 0, stream>>>(x_init, sample_w, sample_b,
                                        ctx_w, ctx_b, bn_g, bn_b,
                                        pool1_w, pool1_b, pool2_w, pool2_b,
                                        bufX, bufH0, bufP1, bufP2, acc);
    // L1: S=512 -> 8 tilesX (3 bits), 32 bands (5 bits) => 2048 blocks
    k_band_ctx<<<2048, 256, 0, stream>>>(bufH0, bufH1, nullptr,
                                         ctx_w + 81,  ctx_b + 3, bn_g + 3, bn_b + 3,
                                         512, 3, 5);
    // L2: S=256 -> 4 tilesX, 16 bands => 512 blocks
    k_band_ctx<<<512, 256, 0, stream>>>(bufH1, bufH2, bufF1,
                                        ctx_w + 162, ctx_b + 6, bn_g + 6, bn_b + 6,
                                        256, 2, 4);
    // L3: S=128 -> 2 tilesX, 8 bands => 128 blocks
    k_band_ctx<<<128, 256, 0, stream>>>(bufH2, nullptr, bufF2,
                                        ctx_w + 243, ctx_b + 9, bn_g + 9, bn_b + 9,
                                        128, 1, 3);
    k_final<<<2048, 256, 0, stream>>>(bufX, bufF1, bufF2, bufP1, bufP2,
                                      thresh, centers, out, acc, out + 1572864);
}

// Round 5
// 223.204 us; speedup vs baseline: 1.2519x; 1.2519x over previous
//
#include <hip/hip_runtime.h>
#include <math.h>

// ---------------------------------------------------------------------------
// LightweightEncoder, round 5.
//  k_band_l0  : per 64x16 x_init band: ctx L0 (h0), sample conv (x, in-block
//               sigma), pool1/pool2 via wave shuffles. Register-array ILP.
//  k_band_ctx : band ctx conv (L1,L2,L3), BN+ReLU at staging, register taps.
//  k_final    : select + soft VQ + counts + hists -> per-block partials
//               (NO global atomics).
//  k_reduce   : 1 block; sums partials, emits esti_cr and hist std.
// LDS band: 17 rows x stride 72, halo-inclusive (LDS col j <-> global col
// gc0-4+j), uniform float4 staging, 16B-aligned rows.
// ---------------------------------------------------------------------------

#define SENT -1e30f      // OOB sentinel: relu(inv*SENT+bb)==0 (pad-after-bnrelu)
#define BSTR 72
#define BCH  (17 * BSTR)

__device__ __forceinline__ float featf(float h) { return 0.5f * (tanhf(h) + 1.0f); }

__device__ __forceinline__ void stage_raw(const float* __restrict__ base,
                                          float* __restrict__ L,
                                          int gr0, int gc0, int S, int t) {
    #pragma unroll
    for (int p = 0; p < 2; p++) {
        int idx = t + 256 * p;
        if (idx < 289) {
            int lr = idx / 17;
            int s  = idx - lr * 17;
            int gr = gr0 + lr;
            int gc = gc0 - 4 + 4 * s;
            float4 v;
            if (gr >= 0 && gr < S && gc >= 0)
                v = *(const float4*)(base + (size_t)gr * S + gc);
            else { v.x = SENT; v.y = SENT; v.z = SENT; v.w = SENT; }
            *(float4*)&L[lr * BSTR + 4 * s] = v;
        }
    }
}

__device__ __forceinline__ void stage_bn(const float* __restrict__ base,
                                         float* __restrict__ L,
                                         int gr0, int gc0, int S, int t,
                                         float inv, float bb) {
    #pragma unroll
    for (int p = 0; p < 2; p++) {
        int idx = t + 256 * p;
        if (idx < 289) {
            int lr = idx / 17;
            int s  = idx - lr * 17;
            int gr = gr0 + lr;
            int gc = gc0 - 4 + 4 * s;
            float4 v;
            if (gr >= 0 && gr < S && gc >= 0)
                v = *(const float4*)(base + (size_t)gr * S + gc);
            else { v.x = SENT; v.y = SENT; v.z = SENT; v.w = SENT; }
            v.x = fmaxf(fmaf(inv, v.x, bb), 0.0f);
            v.y = fmaxf(fmaf(inv, v.y, bb), 0.0f);
            v.z = fmaxf(fmaf(inv, v.z, bb), 0.0f);
            v.w = fmaxf(fmaf(inv, v.w, bb), 0.0f);
            *(float4*)&L[lr * BSTR + 4 * s] = v;
        }
    }
}

// ---------------------------------------------------------------------------
// K0: L0 band kernel. grid = 8 b * 64 bands * 16 tiles = 8192, block 256.
// ---------------------------------------------------------------------------
__global__ __launch_bounds__(256) void k_band_l0(
    const float* __restrict__ xin,
    const float* __restrict__ sw_g, const float* __restrict__ sb,
    const float* __restrict__ ctxw, const float* __restrict__ ctxb,
    const float* __restrict__ bng, const float* __restrict__ bnb,
    const float* __restrict__ p1w, const float* __restrict__ p1b,
    const float* __restrict__ p2w, const float* __restrict__ p2b,
    float* __restrict__ outX, float* __restrict__ outH0,
    float* __restrict__ outP1, float* __restrict__ outP2)
{
    __shared__ float sx[3 * BCH];

    int t = threadIdx.x, bid = blockIdx.x;
    int tileX = bid & 15, bandY = (bid >> 4) & 63, b = bid >> 10;

    int gr0 = bandY * 16 - 1;
    int gc0 = tileX * 64;
    #pragma unroll
    for (int c = 0; c < 3; c++)
        stage_raw(xin + ((size_t)(b * 3 + c) << 20), &sx[c * BCH], gr0, gc0, 1024, t);
    __syncthreads();

    // ---- ctx L0: 32x8 outputs, 1/thread; taps -> regs, then BN, then fma ----
    {
        int ox = t & 31, oy = t >> 5;
        float v[3][9];
        const float* Lb = sx + (2 * oy) * BSTR + 2 * ox + 2;
        #pragma unroll
        for (int c = 0; c < 3; c++) {
            const float* Lc = Lb + c * BCH;
            #pragma unroll
            for (int kh = 0; kh < 3; kh++) {
                float2 u  = *(const float2*)(Lc + kh * BSTR);
                float2 w2 = *(const float2*)(Lc + kh * BSTR + 2);
                v[c][kh * 3 + 0] = u.y;
                v[c][kh * 3 + 1] = w2.x;
                v[c][kh * 3 + 2] = w2.y;
            }
        }
        #pragma unroll
        for (int c = 0; c < 3; c++) {
            float inv = bng[c] / sqrtf(1.001f), bb = bnb[c];
            #pragma unroll
            for (int k = 0; k < 9; k++)
                v[c][k] = fmaxf(fmaf(inv, v[c][k], bb), 0.0f);
        }
        float a0 = ctxb[0], a1 = ctxb[1], a2 = ctxb[2];
        #pragma unroll
        for (int c = 0; c < 3; c++)
            #pragma unroll
            for (int k = 0; k < 9; k++) {
                float tv = v[c][k];
                a0 = fmaf(ctxw[c * 9 + k],      tv, a0);
                a1 = fmaf(ctxw[27 + c * 9 + k], tv, a1);
                a2 = fmaf(ctxw[54 + c * 9 + k], tv, a2);
            }
        unsigned o = (unsigned)(b * 3) * 262144u
                   + (unsigned)(bandY * 8 + oy) * 512u + tileX * 32 + ox;
        outH0[o] = a0; outH0[o + 262144u] = a1; outH0[o + 524288u] = a2;
    }

    // ---- wave 0: sigma + sample conv + pools (shuffle-based, no barriers) ----
    if (t < 64) {
        float p00 = 0.f, p01 = 0.f, p02 = 0.f, p11 = 0.f, p12 = 0.f, p22 = 0.f;
        if (t < 48) {
            float a0 = sw_g[t], a1 = sw_g[48 + t], a2 = sw_g[96 + t];
            p00 = a0 * a0; p01 = a0 * a1; p02 = a0 * a2;
            p11 = a1 * a1; p12 = a1 * a2; p22 = a2 * a2;
        }
        #pragma unroll
        for (int off = 32; off > 0; off >>= 1) {
            p00 += __shfl_down(p00, off); p01 += __shfl_down(p01, off);
            p02 += __shfl_down(p02, off); p11 += __shfl_down(p11, off);
            p12 += __shfl_down(p12, off); p22 += __shfl_down(p22, off);
        }
        float inv_sigma = 0.0f;
        if (t == 0) {
            float q = (p00 + p11 + p22) * (1.0f / 3.0f);
            float pp1 = p01 * p01 + p02 * p02 + p12 * p12;
            float pp2 = (p00 - q) * (p00 - q) + (p11 - q) * (p11 - q)
                      + (p22 - q) * (p22 - q) + 2.0f * pp1;
            float lam;
            if (pp2 < 1e-30f) lam = q;
            else {
                float pr = sqrtf(pp2 / 6.0f);
                float B00 = (p00 - q) / pr, B01 = p01 / pr, B02 = p02 / pr;
                float B11 = (p11 - q) / pr, B12 = p12 / pr, B22 = (p22 - q) / pr;
                float detB = B00 * (B11 * B22 - B12 * B12)
                           - B01 * (B01 * B22 - B12 * B02)
                           + B02 * (B01 * B12 - B11 * B02);
                float r = fminf(1.0f, fmaxf(-1.0f, 0.5f * detB));
                lam = q + 2.0f * pr * cosf(acosf(r) * (1.0f / 3.0f));
            }
            double G00 = p00, G01 = p01, G02 = p02, G11 = p11, G12 = p12, G22 = p22;
            double c2 = G00 + G11 + G22;
            double c1 = G00 * G11 - G01 * G01 + G00 * G22 - G02 * G02 + G11 * G22 - G12 * G12;
            double c0 = G00 * (G11 * G22 - G12 * G12) - G01 * (G01 * G22 - G12 * G02)
                      + G02 * (G01 * G12 - G11 * G02);
            double L = (double)lam;
            #pragma unroll
            for (int it = 0; it < 2; it++) {
                double pv = ((L - c2) * L + c1) * L - c0;
                double dv = (3.0 * L - 2.0 * c2) * L + c1;
                L -= pv / dv;
            }
            inv_sigma = (float)(1.0 / sqrt(L));
        }
        inv_sigma = __shfl(inv_sigma, 0);

        // sample conv: all 48 taps to regs first
        int xl = t & 15, yl = t >> 4;
        float4 r[3][4];
        #pragma unroll
        for (int c = 0; c < 3; c++)
            #pragma unroll
            for (int kh = 0; kh < 4; kh++)
                r[c][kh] = *(const float4*)&sx[c * BCH + (4 * yl + kh + 1) * BSTR + 4 * xl + 4];
        float s0 = 0.f, s1 = 0.f, s2 = 0.f;
        #pragma unroll
        for (int c = 0; c < 3; c++)
            #pragma unroll
            for (int kh = 0; kh < 4; kh++) {
                float4 vv = r[c][kh];
                const float* w0 = &sw_g[(0 * 3 + c) * 16 + kh * 4];
                const float* w1 = &sw_g[(1 * 3 + c) * 16 + kh * 4];
                const float* w2 = &sw_g[(2 * 3 + c) * 16 + kh * 4];
                s0 += w0[0] * vv.x + w0[1] * vv.y + w0[2] * vv.z + w0[3] * vv.w;
                s1 += w1[0] * vv.x + w1[1] * vv.y + w1[2] * vv.z + w1[3] * vv.w;
                s2 += w2[0] * vv.x + w2[1] * vv.y + w2[2] * vv.z + w2[3] * vv.w;
            }
        float x0 = fmaf(s0, inv_sigma, sb[0]);
        float x1 = fmaf(s1, inv_sigma, sb[1]);
        float x2 = fmaf(s2, inv_sigma, sb[2]);
        unsigned o = (unsigned)(b * 3) * 65536u
                   + (unsigned)(bandY * 4 + yl) * 256u + tileX * 16 + xl;
        outX[o] = x0; outX[o + 65536u] = x1; outX[o + 131072u] = x2;

        // pool1 via shuffles: p1(px,py) from x at lanes (2px+dx) + 16*(2py+dy)
        int sl = 2 * (t & 7) + 16 * (2 * ((t >> 3) & 1));
        float q0 = p1b[0], q1 = p1b[1], q2 = p1b[2];
        #pragma unroll
        for (int dy = 0; dy < 2; dy++)
            #pragma unroll
            for (int dx = 0; dx < 2; dx++) {
                int src = sl + dx + 16 * dy;
                float vx0 = __shfl(x0, src);
                float vx1 = __shfl(x1, src);
                float vx2 = __shfl(x2, src);
                int wi = dy * 2 + dx;
                q0 = fmaf(p1w[wi], vx0, q0); q0 = fmaf(p1w[4 + wi],  vx1, q0); q0 = fmaf(p1w[8 + wi],  vx2, q0);
                q1 = fmaf(p1w[12 + wi], vx0, q1); q1 = fmaf(p1w[16 + wi], vx1, q1); q1 = fmaf(p1w[20 + wi], vx2, q1);
                q2 = fmaf(p1w[24 + wi], vx0, q2); q2 = fmaf(p1w[28 + wi], vx1, q2); q2 = fmaf(p1w[32 + wi], vx2, q2);
            }
        if (t < 16) {
            int px = t & 7, py = t >> 3;
            unsigned op = (unsigned)(b * 3) * 16384u
                        + (unsigned)(bandY * 2 + py) * 128u + tileX * 8 + px;
            outP1[op] = q0; outP1[op + 16384u] = q1; outP1[op + 32768u] = q2;
        }

        // pool2 via shuffles from p1 lanes (2px+dx) + 8*dy  (valid lanes 0..15)
        int s2l = 2 * (t & 3);
        float r0 = p2b[0], r1 = p2b[1], r2 = p2b[2];
        #pragma unroll
        for (int dy = 0; dy < 2; dy++)
            #pragma unroll
            for (int dx = 0; dx < 2; dx++) {
                int src = s2l + dx + 8 * dy;
                float vq0 = __shfl(q0, src);
                float vq1 = __shfl(q1, src);
                float vq2 = __shfl(q2, src);
                int wi = dy * 2 + dx;
                r0 = fmaf(p2w[wi], vq0, r0); r0 = fmaf(p2w[4 + wi],  vq1, r0); r0 = fmaf(p2w[8 + wi],  vq2, r0);
                r1 = fmaf(p2w[12 + wi], vq0, r1); r1 = fmaf(p2w[16 + wi], vq1, r1); r1 = fmaf(p2w[20 + wi], vq2, r1);
                r2 = fmaf(p2w[24 + wi], vq0, r2); r2 = fmaf(p2w[28 + wi], vq1, r2); r2 = fmaf(p2w[32 + wi], vq2, r2);
            }
        if (t < 4) {
            unsigned op = (unsigned)(b * 3) * 4096u + (unsigned)bandY * 64u + tileX * 4 + t;
            outP2[op] = r0; outP2[op + 4096u] = r1; outP2[op + 8192u] = r2;
        }
    }
}

// ---------------------------------------------------------------------------
// K1: band ctx conv (L1..L3); BN+ReLU at staging; register taps.
// ---------------------------------------------------------------------------
__global__ __launch_bounds__(256) void k_band_ctx(
    const float* __restrict__ in, float* __restrict__ outH, float* __restrict__ outF,
    const float* __restrict__ w, const float* __restrict__ bias,
    const float* __restrict__ bng, const float* __restrict__ bnb,
    int S, int tpxbits, int bandbits)
{
    __shared__ float sx[3 * BCH];
    int t = threadIdx.x, bid = blockIdx.x;
    int tileX = bid & ((1 << tpxbits) - 1);
    int bandY = (bid >> tpxbits) & ((1 << bandbits) - 1);
    int b = bid >> (tpxbits + bandbits);

    int gr0 = bandY * 16 - 1;
    int gc0 = tileX * 64;
    #pragma unroll
    for (int c = 0; c < 3; c++) {
        float inv = bng[c] / sqrtf(1.001f), bb = bnb[c];
        stage_bn(in + (size_t)(b * 3 + c) * S * S, &sx[c * BCH], gr0, gc0, S, t, inv, bb);
    }
    __syncthreads();

    int So = S >> 1;
    unsigned os = (unsigned)So * So;
    int ox = t & 31, oy = t >> 5;
    float v[3][9];
    const float* Lb = sx + (2 * oy) * BSTR + 2 * ox + 2;
    #pragma unroll
    for (int c = 0; c < 3; c++) {
        const float* Lc = Lb + c * BCH;
        #pragma unroll
        for (int kh = 0; kh < 3; kh++) {
            float2 u  = *(const float2*)(Lc + kh * BSTR);
            float2 w2 = *(const float2*)(Lc + kh * BSTR + 2);
            v[c][kh * 3 + 0] = u.y;
            v[c][kh * 3 + 1] = w2.x;
            v[c][kh * 3 + 2] = w2.y;
        }
    }
    float a0 = bias[0], a1 = bias[1], a2 = bias[2];
    #pragma unroll
    for (int c = 0; c < 3; c++)
        #pragma unroll
        for (int k = 0; k < 9; k++) {
            float tv = v[c][k];
            a0 = fmaf(w[c * 9 + k],      tv, a0);
            a1 = fmaf(w[27 + c * 9 + k], tv, a1);
            a2 = fmaf(w[54 + c * 9 + k], tv, a2);
        }
    unsigned o = (unsigned)(b * 3) * os + (unsigned)(bandY * 8 + oy) * So + tileX * 32 + ox;
    if (outH) { outH[o] = a0; outH[o + os] = a1; outH[o + 2 * os] = a2; }
    if (outF) { outF[o] = featf(a0); outF[o + os] = featf(a1); outF[o + 2 * os] = featf(a2); }
}

// ---------------------------------------------------------------------------
// K2: final select + soft VQ + counts + hists -> per-block partials.
// ---------------------------------------------------------------------------
__device__ __forceinline__ int argmin8(float v, const float* __restrict__ sc) {
    float best = 1e30f; int ki = 0;
    #pragma unroll
    for (int k = 0; k < 8; k++) {
        float df = v - sc[k]; float dk = df * df;
        if (dk < best) { best = dk; ki = k; }
    }
    return ki;
}

__global__ __launch_bounds__(256) void k_final(
    const float* __restrict__ x, const float* __restrict__ f1,
    const float* __restrict__ f2, const float* __restrict__ p1,
    const float* __restrict__ p2, const float* __restrict__ thresh,
    const float* __restrict__ centers, float* __restrict__ out,
    int* __restrict__ partials)
{
    __shared__ int sh[4 * 12];              // per-wave slices: hist[8]+counts[3]+pad
    int t = threadIdx.x;
    int lane = t & 63;
    int* shW = &sh[12 * (t >> 6)];
    if (lane < 12) shW[lane] = 0;
    float sc[8];
    #pragma unroll
    for (int k = 0; k < 8; k++) sc[k] = centers[k];
    __syncthreads();

    float th1 = thresh[0], th2 = thresh[1];
    int gid = blockIdx.x * 256 + t;
    int xc = gid & 255, y = (gid >> 8) & 255, b = gid >> 16;
    unsigned i2 = (unsigned)(((y >> 1) << 7) + (xc >> 1));
    unsigned i4 = (unsigned)(((y >> 2) << 6) + (xc >> 2));
    bool doM1 = ((y & 1) == 0) && ((xc & 1) == 0);
    bool doM2 = ((y & 3) == 0) && ((xc & 3) == 0);
    int c0n = 0, c1n = 0, c2n = 0;

    #pragma unroll
    for (int c = 0; c < 3; c++) {
        unsigned pc = (unsigned)(b * 3 + c);
        float f1v = f1[pc * 16384u + i2];
        float f2v = f2[pc * 4096u + i4];
        float p1v = p1[pc * 16384u + i2];
        float p2v = p2[pc * 4096u + i4];
        float xv  = x[pc * 65536u + (unsigned)((y << 8) + xc)];
        bool cond2 = f2v < th2;
        bool cond1 = (!cond2) && (f1v < th1);
        bool cond0 = !(cond1 || cond2);
        float xq = cond2 ? p2v : (cond1 ? p1v : xv);

        float d[8]; float dmin = 1e30f;
        #pragma unroll
        for (int k = 0; k < 8; k++) { float df = xq - sc[k]; d[k] = df * df; dmin = fminf(dmin, d[k]); }
        float se = 0.f, sn = 0.f;
        #pragma unroll
        for (int k = 0; k < 8; k++) { float e = __expf(dmin - d[k]); se += e; sn = fmaf(sc[k], e, sn); }
        out[pc * 65536u + (unsigned)((y << 8) + xc)] = sn / se;

        c0n += cond0; c1n += cond1; c2n += cond2;

        if (cond0) atomicAdd(&shW[argmin8(xv, sc)], 1);
        if (doM1 && (f2v >= th2) && (f1v < th1)) atomicAdd(&shW[argmin8(p1v, sc)], 1);
        if (doM2 && cond2) atomicAdd(&shW[argmin8(p2v, sc)], 1);
    }
    #pragma unroll
    for (int off = 32; off > 0; off >>= 1) {
        c0n += __shfl_down(c0n, off);
        c1n += __shfl_down(c1n, off);
        c2n += __shfl_down(c2n, off);
    }
    if (lane == 0) { atomicAdd(&shW[8], c0n); atomicAdd(&shW[9], c1n); atomicAdd(&shW[10], c2n); }
    __syncthreads();
    if (t < 12)
        partials[blockIdx.x * 12 + t] = sh[t] + sh[12 + t] + sh[24 + t] + sh[36 + t];
}

// ---------------------------------------------------------------------------
// K3: reduce partials [2048][12] -> scalars. 1 block, 256 threads.
// ---------------------------------------------------------------------------
__global__ void k_reduce(const int* __restrict__ partials, float* __restrict__ out2) {
    __shared__ int accs[12];
    int t = threadIdx.x;
    if (t < 12) accs[t] = 0;
    __syncthreads();
    int s[12];
    #pragma unroll
    for (int k = 0; k < 12; k++) s[k] = 0;
    for (int r = t; r < 2048; r += 256) {
        const int* row = partials + r * 12;
        #pragma unroll
        for (int k = 0; k < 12; k++) s[k] += row[k];
    }
    #pragma unroll
    for (int k = 0; k < 12; k++) {
        #pragma unroll
        for (int off = 32; off > 0; off >>= 1) s[k] += __shfl_down(s[k], off);
    }
    if ((t & 63) == 0) {
        #pragma unroll
        for (int k = 0; k < 12; k++) if (s[k]) atomicAdd(&accs[k], s[k]);
    }
    __syncthreads();
    if (t == 0) {
        float cnt0 = (float)accs[8], cnt1 = (float)accs[9], cnt2 = (float)accs[10];
        float esti = cnt0 + cnt1 * 0.25f + cnt2 * 0.0625f;
        float cr = (1.0f / 16.0f) * esti / (256.0f * 256.0f * 3.0f * 8.0f);
        float cs[8]; float tot = 0.0f;
        #pragma unroll
        for (int k = 0; k < 8; k++) { cs[k] = (float)accs[k]; tot += cs[k]; }
        float mean = 0.0f;
        #pragma unroll
        for (int k = 0; k < 8; k++) { cs[k] /= tot; mean += cs[k]; }
        mean *= 0.125f;
        float var = 0.0f;
        #pragma unroll
        for (int k = 0; k < 8; k++) { float df = cs[k] - mean; var += df * df; }
        var *= (1.0f / 7.0f);
        out2[0] = cr;
        out2[1] = sqrtf(var);
    }
}

extern "C" void kernel_launch(void* const* d_in, const int* in_sizes, int n_in,
                              void* d_out, int out_size, void* d_ws, size_t ws_size,
                              hipStream_t stream) {
    const float* x_init   = (const float*)d_in[0];
    const float* thresh   = (const float*)d_in[1];
    const float* sample_w = (const float*)d_in[2];
    const float* sample_b = (const float*)d_in[3];
    const float* centers  = (const float*)d_in[4];
    const float* pool1_w  = (const float*)d_in[5];
    const float* pool1_b  = (const float*)d_in[6];
    const float* pool2_w  = (const float*)d_in[7];
    const float* pool2_b  = (const float*)d_in[8];
    const float* ctx_w    = (const float*)d_in[9];
    const float* ctx_b    = (const float*)d_in[10];
    const float* bn_g     = (const float*)d_in[11];
    const float* bn_b     = (const float*)d_in[12];
    float* out = (float*)d_out;

    float* wsf      = (float*)d_ws;
    int*   partials = (int*)wsf;               // [2048][12] ints
    float* bufX     = wsf + 32768;             // [8,3,256,256]
    float* bufH0    = bufX  + 1572864;         // [8,3,512,512]
    float* bufH1    = bufH0 + 6291456;         // [8,3,256,256]
    float* bufH2    = bufH1 + 1572864;         // [8,3,128,128]
    float* bufP1    = bufH2 + 393216;          // [8,3,128,128]
    float* bufP2    = bufP1 + 393216;          // [8,3,64,64]
    float* bufF1    = bufP2 + 98304;           // [8,3,128,128]
    float* bufF2    = bufF1 + 393216;          // [8,3,64,64]

    k_band_l0<<<8192, 256, 0, stream>>>(x_init, sample_w, sample_b,
                                        ctx_w, ctx_b, bn_g, bn_b,
                                        pool1_w, pool1_b, pool2_w, pool2_b,
                                        bufX, bufH0, bufP1, bufP2);
    k_band_ctx<<<2048, 256, 0, stream>>>(bufH0, bufH1, nullptr,
                                         ctx_w + 81,  ctx_b + 3, bn_g + 3, bn_b + 3,
                                         512, 3, 5);
    k_band_ctx<<<512, 256, 0, stream>>>(bufH1, bufH2, bufF1,
                                        ctx_w + 162, ctx_b + 6, bn_g + 6, bn_b + 6,
                                        256, 2, 4);
    k_band_ctx<<<128, 256, 0, stream>>>(bufH2, nullptr, bufF2,
                                        ctx_w + 243, ctx_b + 9, bn_g + 9, bn_b + 9,
                                        128, 1, 3);
    k_final<<<2048, 256, 0, stream>>>(bufX, bufF1, bufF2, bufP1, bufP2,
                                      thresh, centers, out, partials);
    k_reduce<<<1, 256, 0, stream>>>(partials, out + 1572864);
}

// Round 6
// 212.952 us; speedup vs baseline: 1.3121x; 1.0481x over previous
//
#include <hip/hip_runtime.h>
#include <math.h>

// ---------------------------------------------------------------------------
// LightweightEncoder, round 6: layer-fused band kernels (halo recompute).
//  k_fused01 : stage 19x67 x_init band -> h0 tile (9x33) in LDS -> h1 out;
//              wave1 does sigma + sample conv (x) + pool1/pool2 (shuffles).
//  k_fused23 : stage 19x67 h1 band -> h2 tile in LDS (writes f1=feat(h2)
//              interior) -> L3 -> f2 out.
//  k_final   : select + soft VQ + counts + hists -> per-block partials.
//  k_reduce  : 1 block; scalars.
// 4 launches. bufH0/bufH2 round-trips eliminated (~50 MB HBM saved).
// ---------------------------------------------------------------------------

#define SENT -1e30f      // OOB sentinel: relu(inv*SENT+bb)==0 (pad-after-bnrelu)
#define SXSTR 72
#define SXCH  (19 * SXSTR)      // staged input plane: 19 rows x 72
#define H0STR 36
#define H0CH  (9 * H0STR)       // mid (h0/h2) plane: 9 rows x 36

__device__ __forceinline__ float featf(float h) { return 0.5f * (tanhf(h) + 1.0f); }

// stage 19 rows x 17 float4 (global cols gc0..gc0+67), raw, SENT at OOB
__device__ __forceinline__ void stage19(const float* __restrict__ base,
                                        float* __restrict__ L,
                                        int gr0, int gc0, int S, int t) {
    #pragma unroll
    for (int p = 0; p < 2; p++) {
        int idx = t + 256 * p;
        if (idx < 323) {
            int lr = idx / 17;
            int s  = idx - lr * 17;
            int gr = gr0 + lr;
            int gc = gc0 + 4 * s;
            float4 v;
            if (gr >= 0 && gr < S && gc >= 0 && gc < S)
                v = *(const float4*)(base + (size_t)gr * S + gc);
            else { v.x = SENT; v.y = SENT; v.z = SENT; v.w = SENT; }
            *(float4*)&L[lr * SXSTR + 4 * s] = v;
        }
    }
}

// ---------------------------------------------------------------------------
// K0: fused ctx L0+L1 + sample + pools. grid = 8 b * 64 bandY * 16 tileX.
// Block covers h1 tile 16x4 (h1 = 256^2), x tile 16x4, p1 8x2, p2 4x1.
// ---------------------------------------------------------------------------
__global__ __launch_bounds__(256) void k_fused01(
    const float* __restrict__ xin,
    const float* __restrict__ sw_g, const float* __restrict__ sb,
    const float* __restrict__ ctxw, const float* __restrict__ ctxb,
    const float* __restrict__ bng, const float* __restrict__ bnb,
    const float* __restrict__ p1w, const float* __restrict__ p1b,
    const float* __restrict__ p2w, const float* __restrict__ p2b,
    float* __restrict__ outX, float* __restrict__ outH1,
    float* __restrict__ outP1, float* __restrict__ outP2)
{
    __shared__ float sx[3 * SXCH];   // raw x_init band
    __shared__ float sm[3 * H0CH];   // h0 tile (raw; SENT at h0-pad positions)

    int t = threadIdx.x, bid = blockIdx.x;
    int tileX = bid & 15, bandY = (bid >> 4) & 63, b = bid >> 10;

    int gr0 = bandY * 16 - 3;
    int gc0 = tileX * 64 - 4;
    #pragma unroll
    for (int c = 0; c < 3; c++)
        stage19(xin + ((size_t)(b * 3 + c) << 20), &sx[c * SXCH], gr0, gc0, 1024, t);
    __syncthreads();

    // ---- L0: h0 tile 9x33 (global rows 8bandY-1.., cols 32tileX-1..) ----
    {
        float inv0[3], bb0[3];
        #pragma unroll
        for (int c = 0; c < 3; c++) { inv0[c] = bng[c] / sqrtf(1.001f); bb0[c] = bnb[c]; }
        #pragma unroll
        for (int p = 0; p < 2; p++) {
            int idx = t + 256 * p;
            if (idx < 297) {
                int lhy = idx / 33;
                int lhx = idx - 33 * lhy;
                bool oob = (bandY == 0 && lhy == 0) || (tileX == 0 && lhx == 0);
                float a0 = ctxb[0], a1 = ctxb[1], a2 = ctxb[2];
                #pragma unroll
                for (int c = 0; c < 3; c++) {
                    const float* basep = &sx[c * SXCH + 2 * lhy * SXSTR + 2 * lhx];
                    float inv = inv0[c], bb = bb0[c];
                    #pragma unroll
                    for (int kh = 0; kh < 3; kh++) {
                        float2 c0 = *(const float2*)(basep + kh * SXSTR);
                        float2 c1 = *(const float2*)(basep + kh * SXSTR + 2);
                        float t0 = fmaxf(fmaf(inv, c0.y, bb), 0.0f);   // col 2lhx+1
                        float t1 = fmaxf(fmaf(inv, c1.x, bb), 0.0f);   // col 2lhx+2
                        float t2 = fmaxf(fmaf(inv, c1.y, bb), 0.0f);   // col 2lhx+3
                        int wi = c * 9 + kh * 3;
                        a0 = fmaf(ctxw[wi], t0, a0); a0 = fmaf(ctxw[wi + 1], t1, a0); a0 = fmaf(ctxw[wi + 2], t2, a0);
                        a1 = fmaf(ctxw[27 + wi], t0, a1); a1 = fmaf(ctxw[28 + wi], t1, a1); a1 = fmaf(ctxw[29 + wi], t2, a1);
                        a2 = fmaf(ctxw[54 + wi], t0, a2); a2 = fmaf(ctxw[55 + wi], t1, a2); a2 = fmaf(ctxw[56 + wi], t2, a2);
                    }
                }
                int o = lhy * H0STR + lhx;
                if (oob) { a0 = SENT; a1 = SENT; a2 = SENT; }
                sm[o] = a0; sm[H0CH + o] = a1; sm[2 * H0CH + o] = a2;
            }
        }
    }
    __syncthreads();

    if (t < 64) {
        // ---- wave0: L1 conv -> h1 (16x4 tile) ----
        int lx = t & 15, ly = t >> 4;
        const float* w1c = ctxw + 81;
        float a0 = ctxb[3], a1 = ctxb[4], a2 = ctxb[5];
        #pragma unroll
        for (int c = 0; c < 3; c++) {
            float inv = bng[3 + c] / sqrtf(1.001f), bb = bnb[3 + c];
            const float* mb = &sm[c * H0CH + 2 * ly * H0STR + 2 * lx];
            #pragma unroll
            for (int kh = 0; kh < 3; kh++) {
                float2 c0 = *(const float2*)(mb + kh * H0STR);
                float c2v = mb[kh * H0STR + 2];
                float t0 = fmaxf(fmaf(inv, c0.x, bb), 0.0f);
                float t1 = fmaxf(fmaf(inv, c0.y, bb), 0.0f);
                float t2 = fmaxf(fmaf(inv, c2v, bb), 0.0f);
                int wi = c * 9 + kh * 3;
                a0 = fmaf(w1c[wi], t0, a0); a0 = fmaf(w1c[wi + 1], t1, a0); a0 = fmaf(w1c[wi + 2], t2, a0);
                a1 = fmaf(w1c[27 + wi], t0, a1); a1 = fmaf(w1c[28 + wi], t1, a1); a1 = fmaf(w1c[29 + wi], t2, a1);
                a2 = fmaf(w1c[54 + wi], t0, a2); a2 = fmaf(w1c[55 + wi], t1, a2); a2 = fmaf(w1c[56 + wi], t2, a2);
            }
        }
        unsigned o = (unsigned)(b * 3) * 65536u + (unsigned)(bandY * 4 + ly) * 256u + tileX * 16 + lx;
        outH1[o] = a0; outH1[o + 65536u] = a1; outH1[o + 131072u] = a2;
    } else if (t < 128) {
        int tl = t - 64;
        // ---- wave1: sigma (lane-parallel Gram + lane-0 eig) ----
        float p00 = 0.f, p01 = 0.f, p02 = 0.f, p11 = 0.f, p12 = 0.f, p22 = 0.f;
        if (tl < 48) {
            float a0 = sw_g[tl], a1 = sw_g[48 + tl], a2 = sw_g[96 + tl];
            p00 = a0 * a0; p01 = a0 * a1; p02 = a0 * a2;
            p11 = a1 * a1; p12 = a1 * a2; p22 = a2 * a2;
        }
        #pragma unroll
        for (int off = 32; off > 0; off >>= 1) {
            p00 += __shfl_down(p00, off); p01 += __shfl_down(p01, off);
            p02 += __shfl_down(p02, off); p11 += __shfl_down(p11, off);
            p12 += __shfl_down(p12, off); p22 += __shfl_down(p22, off);
        }
        float inv_sigma = 0.0f;
        if (tl == 0) {
            float q = (p00 + p11 + p22) * (1.0f / 3.0f);
            float pp1 = p01 * p01 + p02 * p02 + p12 * p12;
            float pp2 = (p00 - q) * (p00 - q) + (p11 - q) * (p11 - q)
                      + (p22 - q) * (p22 - q) + 2.0f * pp1;
            float lam;
            if (pp2 < 1e-30f) lam = q;
            else {
                float pr = sqrtf(pp2 / 6.0f);
                float B00 = (p00 - q) / pr, B01 = p01 / pr, B02 = p02 / pr;
                float B11 = (p11 - q) / pr, B12 = p12 / pr, B22 = (p22 - q) / pr;
                float detB = B00 * (B11 * B22 - B12 * B12)
                           - B01 * (B01 * B22 - B12 * B02)
                           + B02 * (B01 * B12 - B11 * B02);
                float r = fminf(1.0f, fmaxf(-1.0f, 0.5f * detB));
                lam = q + 2.0f * pr * cosf(acosf(r) * (1.0f / 3.0f));
            }
            double G00 = p00, G01 = p01, G02 = p02, G11 = p11, G12 = p12, G22 = p22;
            double c2 = G00 + G11 + G22;
            double c1 = G00 * G11 - G01 * G01 + G00 * G22 - G02 * G02 + G11 * G22 - G12 * G12;
            double c0 = G00 * (G11 * G22 - G12 * G12) - G01 * (G01 * G22 - G12 * G02)
                      + G02 * (G01 * G12 - G11 * G02);
            double L = (double)lam;
            #pragma unroll
            for (int it = 0; it < 2; it++) {
                double pv = ((L - c2) * L + c1) * L - c0;
                double dv = (3.0 * L - 2.0 * c2) * L + c1;
                L -= pv / dv;
            }
            inv_sigma = (float)(1.0 / sqrt(L));
        }
        inv_sigma = __shfl(inv_sigma, 0);

        // ---- sample conv: x tile 16x4 (rows 4bandY.., cols 16tileX..) ----
        int xl = tl & 15, yl = tl >> 4;
        float4 r[3][4];
        #pragma unroll
        for (int c = 0; c < 3; c++)
            #pragma unroll
            for (int kh = 0; kh < 4; kh++)
                r[c][kh] = *(const float4*)&sx[c * SXCH + (4 * yl + 3 + kh) * SXSTR + 4 * xl + 4];
        float s0 = 0.f, s1 = 0.f, s2 = 0.f;
        #pragma unroll
        for (int c = 0; c < 3; c++)
            #pragma unroll
            for (int kh = 0; kh < 4; kh++) {
                float4 vv = r[c][kh];
                const float* w0 = &sw_g[(0 * 3 + c) * 16 + kh * 4];
                const float* w1 = &sw_g[(1 * 3 + c) * 16 + kh * 4];
                const float* w2 = &sw_g[(2 * 3 + c) * 16 + kh * 4];
                s0 += w0[0] * vv.x + w0[1] * vv.y + w0[2] * vv.z + w0[3] * vv.w;
                s1 += w1[0] * vv.x + w1[1] * vv.y + w1[2] * vv.z + w1[3] * vv.w;
                s2 += w2[0] * vv.x + w2[1] * vv.y + w2[2] * vv.z + w2[3] * vv.w;
            }
        float x0 = fmaf(s0, inv_sigma, sb[0]);
        float x1 = fmaf(s1, inv_sigma, sb[1]);
        float x2 = fmaf(s2, inv_sigma, sb[2]);
        unsigned o = (unsigned)(b * 3) * 65536u + (unsigned)(bandY * 4 + yl) * 256u + tileX * 16 + xl;
        outX[o] = x0; outX[o + 65536u] = x1; outX[o + 131072u] = x2;

        // ---- pool1 via shuffles ----
        int sl = 2 * (tl & 7) + 32 * ((tl >> 3) & 1);
        float q0 = p1b[0], q1 = p1b[1], q2 = p1b[2];
        #pragma unroll
        for (int dy = 0; dy < 2; dy++)
            #pragma unroll
            for (int dx = 0; dx < 2; dx++) {
                int src = sl + dx + 16 * dy;
                float vx0 = __shfl(x0, src);
                float vx1 = __shfl(x1, src);
                float vx2 = __shfl(x2, src);
                int wi = dy * 2 + dx;
                q0 = fmaf(p1w[wi], vx0, q0); q0 = fmaf(p1w[4 + wi],  vx1, q0); q0 = fmaf(p1w[8 + wi],  vx2, q0);
                q1 = fmaf(p1w[12 + wi], vx0, q1); q1 = fmaf(p1w[16 + wi], vx1, q1); q1 = fmaf(p1w[20 + wi], vx2, q1);
                q2 = fmaf(p1w[24 + wi], vx0, q2); q2 = fmaf(p1w[28 + wi], vx1, q2); q2 = fmaf(p1w[32 + wi], vx2, q2);
            }
        if (tl < 16) {
            int px = tl & 7, py = tl >> 3;
            unsigned op = (unsigned)(b * 3) * 16384u + (unsigned)(bandY * 2 + py) * 128u + tileX * 8 + px;
            outP1[op] = q0; outP1[op + 16384u] = q1; outP1[op + 32768u] = q2;
        }

        // ---- pool2 via shuffles (p1 values live on lanes 0..15) ----
        int s2l = 2 * (tl & 3);
        float r0 = p2b[0], r1 = p2b[1], r2 = p2b[2];
        #pragma unroll
        for (int dy = 0; dy < 2; dy++)
            #pragma unroll
            for (int dx = 0; dx < 2; dx++) {
                int src = s2l + dx + 8 * dy;
                float vq0 = __shfl(q0, src);
                float vq1 = __shfl(q1, src);
                float vq2 = __shfl(q2, src);
                int wi = dy * 2 + dx;
                r0 = fmaf(p2w[wi], vq0, r0); r0 = fmaf(p2w[4 + wi],  vq1, r0); r0 = fmaf(p2w[8 + wi],  vq2, r0);
                r1 = fmaf(p2w[12 + wi], vq0, r1); r1 = fmaf(p2w[16 + wi], vq1, r1); r1 = fmaf(p2w[20 + wi], vq2, r1);
                r2 = fmaf(p2w[24 + wi], vq0, r2); r2 = fmaf(p2w[28 + wi], vq1, r2); r2 = fmaf(p2w[32 + wi], vq2, r2);
            }
        if (tl < 4) {
            unsigned op = (unsigned)(b * 3) * 4096u + (unsigned)bandY * 64u + tileX * 4 + tl;
            outP2[op] = r0; outP2[op + 4096u] = r1; outP2[op + 8192u] = r2;
        }
    }
}

// ---------------------------------------------------------------------------
// K1: fused ctx L2+L3. grid = 8 b * 16 bandY * 4 tileX = 512.
// Block covers f2 tile 16x4 (64^2); writes f1 interior 8x32 (128^2).
// ---------------------------------------------------------------------------
__global__ __launch_bounds__(256) void k_fused23(
    const float* __restrict__ h1, float* __restrict__ outF1, float* __restrict__ outF2,
    const float* __restrict__ ctxw, const float* __restrict__ ctxb,
    const float* __restrict__ bng, const float* __restrict__ bnb)
{
    __shared__ float sx[3 * SXCH];   // raw h1 band
    __shared__ float sm[3 * H0CH];   // h2 tile (raw; SENT pads)

    int t = threadIdx.x, bid = blockIdx.x;
    int tileX = bid & 3, bandY = (bid >> 2) & 15, b = bid >> 6;

    int gr0 = bandY * 16 - 3;
    int gc0 = tileX * 64 - 4;
    #pragma unroll
    for (int c = 0; c < 3; c++)
        stage19(h1 + (size_t)(b * 3 + c) * 65536, &sx[c * SXCH], gr0, gc0, 256, t);
    __syncthreads();

    // ---- L2: h2 tile 9x33; write f1 = feat(h2) for owned interior 8x32 ----
    {
        const float* w2c = ctxw + 162;
        float inv2[3], bb2[3];
        #pragma unroll
        for (int c = 0; c < 3; c++) { inv2[c] = bng[6 + c] / sqrtf(1.001f); bb2[c] = bnb[6 + c]; }
        #pragma unroll
        for (int p = 0; p < 2; p++) {
            int idx = t + 256 * p;
            if (idx < 297) {
                int lhy = idx / 33;
                int lhx = idx - 33 * lhy;
                bool oob = (bandY == 0 && lhy == 0) || (tileX == 0 && lhx == 0);
                float a0 = ctxb[6], a1 = ctxb[7], a2 = ctxb[8];
                #pragma unroll
                for (int c = 0; c < 3; c++) {
                    const float* basep = &sx[c * SXCH + 2 * lhy * SXSTR + 2 * lhx];
                    float inv = inv2[c], bb = bb2[c];
                    #pragma unroll
                    for (int kh = 0; kh < 3; kh++) {
                        float2 c0 = *(const float2*)(basep + kh * SXSTR);
                        float2 c1 = *(const float2*)(basep + kh * SXSTR + 2);
                        float t0 = fmaxf(fmaf(inv, c0.y, bb), 0.0f);
                        float t1 = fmaxf(fmaf(inv, c1.x, bb), 0.0f);
                        float t2 = fmaxf(fmaf(inv, c1.y, bb), 0.0f);
                        int wi = c * 9 + kh * 3;
                        a0 = fmaf(w2c[wi], t0, a0); a0 = fmaf(w2c[wi + 1], t1, a0); a0 = fmaf(w2c[wi + 2], t2, a0);
                        a1 = fmaf(w2c[27 + wi], t0, a1); a1 = fmaf(w2c[28 + wi], t1, a1); a1 = fmaf(w2c[29 + wi], t2, a1);
                        a2 = fmaf(w2c[54 + wi], t0, a2); a2 = fmaf(w2c[55 + wi], t1, a2); a2 = fmaf(w2c[56 + wi], t2, a2);
                    }
                }
                int o = lhy * H0STR + lhx;
                if (!oob && lhy >= 1 && lhx >= 1) {
                    unsigned fo = (unsigned)(b * 3) * 16384u
                                + (unsigned)(8 * bandY + lhy - 1) * 128u + 32 * tileX + lhx - 1;
                    outF1[fo] = featf(a0); outF1[fo + 16384u] = featf(a1); outF1[fo + 32768u] = featf(a2);
                }
                if (oob) { a0 = SENT; a1 = SENT; a2 = SENT; }
                sm[o] = a0; sm[H0CH + o] = a1; sm[2 * H0CH + o] = a2;
            }
        }
    }
    __syncthreads();

    if (t < 64) {
        // ---- L3 -> f2 (16x4 tile) ----
        int lx = t & 15, ly = t >> 4;
        const float* w3c = ctxw + 243;
        float a0 = ctxb[9], a1 = ctxb[10], a2 = ctxb[11];
        #pragma unroll
        for (int c = 0; c < 3; c++) {
            float inv = bng[9 + c] / sqrtf(1.001f), bb = bnb[9 + c];
            const float* mb = &sm[c * H0CH + 2 * ly * H0STR + 2 * lx];
            #pragma unroll
            for (int kh = 0; kh < 3; kh++) {
                float2 c0 = *(const float2*)(mb + kh * H0STR);
                float c2v = mb[kh * H0STR + 2];
                float t0 = fmaxf(fmaf(inv, c0.x, bb), 0.0f);
                float t1 = fmaxf(fmaf(inv, c0.y, bb), 0.0f);
                float t2 = fmaxf(fmaf(inv, c2v, bb), 0.0f);
                int wi = c * 9 + kh * 3;
                a0 = fmaf(w3c[wi], t0, a0); a0 = fmaf(w3c[wi + 1], t1, a0); a0 = fmaf(w3c[wi + 2], t2, a0);
                a1 = fmaf(w3c[27 + wi], t0, a1); a1 = fmaf(w3c[28 + wi], t1, a1); a1 = fmaf(w3c[29 + wi], t2, a1);
                a2 = fmaf(w3c[54 + wi], t0, a2); a2 = fmaf(w3c[55 + wi], t1, a2); a2 = fmaf(w3c[56 + wi], t2, a2);
            }
        }
        unsigned o = (unsigned)(b * 3) * 4096u + (unsigned)(bandY * 4 + ly) * 64u + tileX * 16 + lx;
        outF2[o] = featf(a0); outF2[o + 4096u] = featf(a1); outF2[o + 8192u] = featf(a2);
    }
}

// ---------------------------------------------------------------------------
// K2: final select + soft VQ + counts + hists -> per-block partials.
// ---------------------------------------------------------------------------
__device__ __forceinline__ int argmin8(float v, const float* __restrict__ sc) {
    float best = 1e30f; int ki = 0;
    #pragma unroll
    for (int k = 0; k < 8; k++) {
        float df = v - sc[k]; float dk = df * df;
        if (dk < best) { best = dk; ki = k; }
    }
    return ki;
}

__global__ __launch_bounds__(256) void k_final(
    const float* __restrict__ x, const float* __restrict__ f1,
    const float* __restrict__ f2, const float* __restrict__ p1,
    const float* __restrict__ p2, const float* __restrict__ thresh,
    const float* __restrict__ centers, float* __restrict__ out,
    int* __restrict__ partials)
{
    __shared__ int sh[4 * 12];
    int t = threadIdx.x;
    int lane = t & 63;
    int* shW = &sh[12 * (t >> 6)];
    if (lane < 12) shW[lane] = 0;
    float sc[8];
    #pragma unroll
    for (int k = 0; k < 8; k++) sc[k] = centers[k];
    __syncthreads();

    float th1 = thresh[0], th2 = thresh[1];
    int gid = blockIdx.x * 256 + t;
    int xc = gid & 255, y = (gid >> 8) & 255, b = gid >> 16;
    unsigned i2 = (unsigned)(((y >> 1) << 7) + (xc >> 1));
    unsigned i4 = (unsigned)(((y >> 2) << 6) + (xc >> 2));
    bool doM1 = ((y & 1) == 0) && ((xc & 1) == 0);
    bool doM2 = ((y & 3) == 0) && ((xc & 3) == 0);
    int c0n = 0, c1n = 0, c2n = 0;

    #pragma unroll
    for (int c = 0; c < 3; c++) {
        unsigned pc = (unsigned)(b * 3 + c);
        float f1v = f1[pc * 16384u + i2];
        float f2v = f2[pc * 4096u + i4];
        float p1v = p1[pc * 16384u + i2];
        float p2v = p2[pc * 4096u + i4];
        float xv  = x[pc * 65536u + (unsigned)((y << 8) + xc)];
        bool cond2 = f2v < th2;
        bool cond1 = (!cond2) && (f1v < th1);
        bool cond0 = !(cond1 || cond2);
        float xq = cond2 ? p2v : (cond1 ? p1v : xv);

        float d[8]; float dmin = 1e30f;
        #pragma unroll
        for (int k = 0; k < 8; k++) { float df = xq - sc[k]; d[k] = df * df; dmin = fminf(dmin, d[k]); }
        float se = 0.f, sn = 0.f;
        #pragma unroll
        for (int k = 0; k < 8; k++) { float e = __expf(dmin - d[k]); se += e; sn = fmaf(sc[k], e, sn); }
        out[pc * 65536u + (unsigned)((y << 8) + xc)] = sn / se;

        c0n += cond0; c1n += cond1; c2n += cond2;

        if (cond0) atomicAdd(&shW[argmin8(xv, sc)], 1);
        if (doM1 && (f2v >= th2) && (f1v < th1)) atomicAdd(&shW[argmin8(p1v, sc)], 1);
        if (doM2 && cond2) atomicAdd(&shW[argmin8(p2v, sc)], 1);
    }
    #pragma unroll
    for (int off = 32; off > 0; off >>= 1) {
        c0n += __shfl_down(c0n, off);
        c1n += __shfl_down(c1n, off);
        c2n += __shfl_down(c2n, off);
    }
    if (lane == 0) { atomicAdd(&shW[8], c0n); atomicAdd(&shW[9], c1n); atomicAdd(&shW[10], c2n); }
    __syncthreads();
    if (t < 12)
        partials[blockIdx.x * 12 + t] = sh[t] + sh[12 + t] + sh[24 + t] + sh[36 + t];
}

// ---------------------------------------------------------------------------
// K3: reduce partials [2048][12] -> scalars. 1 block, 256 threads.
// ---------------------------------------------------------------------------
__global__ void k_reduce(const int* __restrict__ partials, float* __restrict__ out2) {
    __shared__ int accs[12];
    int t = threadIdx.x;
    if (t < 12) accs[t] = 0;
    __syncthreads();
    int s[12];
    #pragma unroll
    for (int k = 0; k < 12; k++) s[k] = 0;
    for (int r = t; r < 2048; r += 256) {
        const int* row = partials + r * 12;
        #pragma unroll
        for (int k = 0; k < 12; k++) s[k] += row[k];
    }
    #pragma unroll
    for (int k = 0; k < 12; k++) {
        #pragma unroll
        for (int off = 32; off > 0; off >>= 1) s[k] += __shfl_down(s[k], off);
    }
    if ((t & 63) == 0) {
        #pragma unroll
        for (int k = 0; k < 12; k++) if (s[k]) atomicAdd(&accs[k], s[k]);
    }
    __syncthreads();
    if (t == 0) {
        float cnt0 = (float)accs[8], cnt1 = (float)accs[9], cnt2 = (float)accs[10];
        float esti = cnt0 + cnt1 * 0.25f + cnt2 * 0.0625f;
        float cr = (1.0f / 16.0f) * esti / (256.0f * 256.0f * 3.0f * 8.0f);
        float cs[8]; float tot = 0.0f;
        #pragma unroll
        for (int k = 0; k < 8; k++) { cs[k] = (float)accs[k]; tot += cs[k]; }
        float mean = 0.0f;
        #pragma unroll
        for (int k = 0; k < 8; k++) { cs[k] /= tot; mean += cs[k]; }
        mean *= 0.125f;
        float var = 0.0f;
        #pragma unroll
        for (int k = 0; k < 8; k++) { float df = cs[k] - mean; var += df * df; }
        var *= (1.0f / 7.0f);
        out2[0] = cr;
        out2[1] = sqrtf(var);
    }
}

extern "C" void kernel_launch(void* const* d_in, const int* in_sizes, int n_in,
                              void* d_out, int out_size, void* d_ws, size_t ws_size,
                              hipStream_t stream) {
    const float* x_init   = (const float*)d_in[0];
    const float* thresh   = (const float*)d_in[1];
    const float* sample_w = (const float*)d_in[2];
    const float* sample_b = (const float*)d_in[3];
    const float* centers  = (const float*)d_in[4];
    const float* pool1_w  = (const float*)d_in[5];
    const float* pool1_b  = (const float*)d_in[6];
    const float* pool2_w  = (const float*)d_in[7];
    const float* pool2_b  = (const float*)d_in[8];
    const float* ctx_w    = (const float*)d_in[9];
    const float* ctx_b    = (const float*)d_in[10];
    const float* bn_g     = (const float*)d_in[11];
    const float* bn_b     = (const float*)d_in[12];
    float* out = (float*)d_out;

    float* wsf      = (float*)d_ws;
    int*   partials = (int*)wsf;               // [2048][12] ints
    float* bufX     = wsf + 32768;             // [8,3,256,256]
    float* bufH1    = bufX  + 1572864;         // [8,3,256,256]
    float* bufP1    = bufH1 + 1572864;         // [8,3,128,128]
    float* bufP2    = bufP1 + 393216;          // [8,3,64,64]
    float* bufF1    = bufP2 + 98304;           // [8,3,128,128]
    float* bufF2    = bufF1 + 393216;          // [8,3,64,64]

    k_fused01<<<8192, 256, 0, stream>>>(x_init, sample_w, sample_b,
                                        ctx_w, ctx_b, bn_g, bn_b,
                                        pool1_w, pool1_b, pool2_w, pool2_b,
                                        bufX, bufH1, bufP1, bufP2);
    k_fused23<<<512, 256, 0, stream>>>(bufH1, bufF1, bufF2,
                                       ctx_w, ctx_b, bn_g, bn_b);
    k_final<<<2048, 256, 0, stream>>>(bufX, bufF1, bufF2, bufP1, bufP2,
                                      thresh, centers, out, partials);
    k_reduce<<<1, 256, 0, stream>>>(partials, out + 1572864);
}

// Round 7
// 206.501 us; speedup vs baseline: 1.3531x; 1.0312x over previous
//
#include <hip/hip_runtime.h>
#include <math.h>

// ---------------------------------------------------------------------------
// LightweightEncoder, round 7: k_fused01 staging via global_load_lds DMA.
//  k_fused01 : DMA-stage 19x68 x_init band (stride 68 = 17 float4 slots/row,
//              slot-linear layout) -> h0 tile (9x33) in LDS -> h1 out;
//              wave1: sigma + sample conv (x) + pool1/pool2 (shuffles).
//              OOB: clamped addresses + SENT fixup on edge blocks only.
//  k_fused23 : unchanged from R6 (legacy staged path).
//  k_final   : unchanged (per-block partials).
//  k_reduce  : unchanged.
// ---------------------------------------------------------------------------

#define SENT -1e30f      // OOB sentinel: relu(inv*SENT+bb)==0 (pad-after-bnrelu)

// fused01 DMA layout: 19 rows x 68 floats (17 float4 slots), 323 slots/plane
#define DSTR 68
#define DPLANE 1292            // 323 * 4 floats

// fused23 legacy layout
#define SXSTR 72
#define SXCH  (19 * SXSTR)
#define H0STR 36
#define H0CH  (9 * H0STR)

__device__ __forceinline__ float featf(float h) { return 0.5f * (tanhf(h) + 1.0f); }

__device__ __forceinline__ void dma16(const float* g, float* l) {
    __builtin_amdgcn_global_load_lds((const __attribute__((address_space(1))) void*)g,
                                     (__attribute__((address_space(3))) void*)l,
                                     16, 0, 0);
}

// legacy staging for fused23
__device__ __forceinline__ void stage19(const float* __restrict__ base,
                                        float* __restrict__ L,
                                        int gr0, int gc0, int S, int t) {
    #pragma unroll
    for (int p = 0; p < 2; p++) {
        int idx = t + 256 * p;
        if (idx < 323) {
            int lr = idx / 17;
            int s  = idx - lr * 17;
            int gr = gr0 + lr;
            int gc = gc0 + 4 * s;
            float4 v;
            if (gr >= 0 && gr < S && gc >= 0 && gc < S)
                v = *(const float4*)(base + (size_t)gr * S + gc);
            else { v.x = SENT; v.y = SENT; v.z = SENT; v.w = SENT; }
            *(float4*)&L[lr * SXSTR + 4 * s] = v;
        }
    }
}

// ---------------------------------------------------------------------------
// K0: fused ctx L0+L1 + sample + pools. grid = 8 b * 64 bandY * 16 tileX.
// ---------------------------------------------------------------------------
__global__ __launch_bounds__(256) void k_fused01(
    const float* __restrict__ xin,
    const float* __restrict__ sw_g, const float* __restrict__ sb,
    const float* __restrict__ ctxw, const float* __restrict__ ctxb,
    const float* __restrict__ bng, const float* __restrict__ bnb,
    const float* __restrict__ p1w, const float* __restrict__ p1b,
    const float* __restrict__ p2w, const float* __restrict__ p2b,
    float* __restrict__ outX, float* __restrict__ outH1,
    float* __restrict__ outP1, float* __restrict__ outP2)
{
    __shared__ float sx[3 * DPLANE];   // raw x_init band, slot-linear
    __shared__ float sm[3 * H0CH];     // h0 tile (raw; SENT at pad positions)

    int t = threadIdx.x, bid = blockIdx.x;
    int tileX = bid & 15, bandY = (bid >> 4) & 63, b = bid >> 10;

    int gr0 = bandY * 16 - 3;
    int gc0 = tileX * 64 - 4;

    // ---- DMA staging: wave-uniform LDS base + lane*16, per-lane global addr ----
    {
        int slot0 = t;               // p = 0
        int lr0 = slot0 / 17, cs0 = slot0 - 17 * lr0;
        int slot1 = t + 256;         // p = 1 (valid when t < 67)
        int lr1 = slot1 / 17, cs1 = slot1 - 17 * lr1;
        int grA = min(max(gr0 + lr0, 0), 1023);
        int gcA = min(max(gc0 + 4 * cs0, 0), 1020);
        int grB = min(max(gr0 + lr1, 0), 1023);
        int gcB = min(max(gc0 + 4 * cs1, 0), 1020);
        int offA = (grA << 10) + gcA;
        int offB = (grB << 10) + gcB;
        int wbase = t & 192;         // 64 * wave_id
        #pragma unroll
        for (int c = 0; c < 3; c++) {
            const float* plane = xin + ((size_t)(b * 3 + c) << 20);
            dma16(plane + offA, &sx[c * DPLANE + 4 * wbase]);
            if (t < 67) dma16(plane + offB, &sx[c * DPLANE + 4 * (256 + wbase)]);
        }
    }
    __syncthreads();   // compiler drains vmcnt before s_barrier -> DMA complete

    // ---- SENT fixup on edge blocks (block-uniform branch) ----
    if (tileX == 0 || bandY == 0) {
        float4 sv; sv.x = SENT; sv.y = SENT; sv.z = SENT; sv.w = SENT;
        if (bandY == 0 && t < 153) {      // rows 0..2 (global rows -3..-1), all slots
            int c = t / 51, rem = t - 51 * c;
            int lr = rem / 17, cs = rem - 17 * lr;
            *(float4*)&sx[c * DPLANE + lr * DSTR + 4 * cs] = sv;
        }
        if (tileX == 0 && t >= 192 && t < 249) {   // col slot 0 of each row (cols -4..-1)
            int u = t - 192;
            int c = u / 19, lr = u - 19 * c;
            *(float4*)&sx[c * DPLANE + lr * DSTR] = sv;
        }
        __syncthreads();
    }

    // ---- L0: h0 tile 9x33 (global rows 8bandY-1.., cols 32tileX-1..) ----
    {
        float inv0[3], bb0[3];
        #pragma unroll
        for (int c = 0; c < 3; c++) { inv0[c] = bng[c] / sqrtf(1.001f); bb0[c] = bnb[c]; }
        #pragma unroll
        for (int p = 0; p < 2; p++) {
            int idx = t + 256 * p;
            if (idx < 297) {
                int lhy = idx / 33;
                int lhx = idx - 33 * lhy;
                bool oob = (bandY == 0 && lhy == 0) || (tileX == 0 && lhx == 0);
                float a0 = ctxb[0], a1 = ctxb[1], a2 = ctxb[2];
                #pragma unroll
                for (int c = 0; c < 3; c++) {
                    const float* basep = &sx[c * DPLANE + 2 * lhy * DSTR + 2 * lhx];
                    float inv = inv0[c], bb = bb0[c];
                    #pragma unroll
                    for (int kh = 0; kh < 3; kh++) {
                        float2 c0 = *(const float2*)(basep + kh * DSTR);
                        float2 c1 = *(const float2*)(basep + kh * DSTR + 2);
                        float t0 = fmaxf(fmaf(inv, c0.y, bb), 0.0f);   // col 2lhx+1
                        float t1 = fmaxf(fmaf(inv, c1.x, bb), 0.0f);   // col 2lhx+2
                        float t2 = fmaxf(fmaf(inv, c1.y, bb), 0.0f);   // col 2lhx+3
                        int wi = c * 9 + kh * 3;
                        a0 = fmaf(ctxw[wi], t0, a0); a0 = fmaf(ctxw[wi + 1], t1, a0); a0 = fmaf(ctxw[wi + 2], t2, a0);
                        a1 = fmaf(ctxw[27 + wi], t0, a1); a1 = fmaf(ctxw[28 + wi], t1, a1); a1 = fmaf(ctxw[29 + wi], t2, a1);
                        a2 = fmaf(ctxw[54 + wi], t0, a2); a2 = fmaf(ctxw[55 + wi], t1, a2); a2 = fmaf(ctxw[56 + wi], t2, a2);
                    }
                }
                int o = lhy * H0STR + lhx;
                if (oob) { a0 = SENT; a1 = SENT; a2 = SENT; }
                sm[o] = a0; sm[H0CH + o] = a1; sm[2 * H0CH + o] = a2;
            }
        }
    }
    __syncthreads();

    if (t < 64) {
        // ---- wave0: L1 conv -> h1 (16x4 tile) ----
        int lx = t & 15, ly = t >> 4;
        const float* w1c = ctxw + 81;
        float a0 = ctxb[3], a1 = ctxb[4], a2 = ctxb[5];
        #pragma unroll
        for (int c = 0; c < 3; c++) {
            float inv = bng[3 + c] / sqrtf(1.001f), bb = bnb[3 + c];
            const float* mb = &sm[c * H0CH + 2 * ly * H0STR + 2 * lx];
            #pragma unroll
            for (int kh = 0; kh < 3; kh++) {
                float2 c0 = *(const float2*)(mb + kh * H0STR);
                float c2v = mb[kh * H0STR + 2];
                float t0 = fmaxf(fmaf(inv, c0.x, bb), 0.0f);
                float t1 = fmaxf(fmaf(inv, c0.y, bb), 0.0f);
                float t2 = fmaxf(fmaf(inv, c2v, bb), 0.0f);
                int wi = c * 9 + kh * 3;
                a0 = fmaf(w1c[wi], t0, a0); a0 = fmaf(w1c[wi + 1], t1, a0); a0 = fmaf(w1c[wi + 2], t2, a0);
                a1 = fmaf(w1c[27 + wi], t0, a1); a1 = fmaf(w1c[28 + wi], t1, a1); a1 = fmaf(w1c[29 + wi], t2, a1);
                a2 = fmaf(w1c[54 + wi], t0, a2); a2 = fmaf(w1c[55 + wi], t1, a2); a2 = fmaf(w1c[56 + wi], t2, a2);
            }
        }
        unsigned o = (unsigned)(b * 3) * 65536u + (unsigned)(bandY * 4 + ly) * 256u + tileX * 16 + lx;
        outH1[o] = a0; outH1[o + 65536u] = a1; outH1[o + 131072u] = a2;
    } else if (t < 128) {
        int tl = t - 64;
        // ---- wave1: sigma (lane-parallel Gram + lane-0 eig) ----
        float p00 = 0.f, p01 = 0.f, p02 = 0.f, p11 = 0.f, p12 = 0.f, p22 = 0.f;
        if (tl < 48) {
            float a0 = sw_g[tl], a1 = sw_g[48 + tl], a2 = sw_g[96 + tl];
            p00 = a0 * a0; p01 = a0 * a1; p02 = a0 * a2;
            p11 = a1 * a1; p12 = a1 * a2; p22 = a2 * a2;
        }
        #pragma unroll
        for (int off = 32; off > 0; off >>= 1) {
            p00 += __shfl_down(p00, off); p01 += __shfl_down(p01, off);
            p02 += __shfl_down(p02, off); p11 += __shfl_down(p11, off);
            p12 += __shfl_down(p12, off); p22 += __shfl_down(p22, off);
        }
        float inv_sigma = 0.0f;
        if (tl == 0) {
            float q = (p00 + p11 + p22) * (1.0f / 3.0f);
            float pp1 = p01 * p01 + p02 * p02 + p12 * p12;
            float pp2 = (p00 - q) * (p00 - q) + (p11 - q) * (p11 - q)
                      + (p22 - q) * (p22 - q) + 2.0f * pp1;
            float lam;
            if (pp2 < 1e-30f) lam = q;
            else {
                float pr = sqrtf(pp2 / 6.0f);
                float B00 = (p00 - q) / pr, B01 = p01 / pr, B02 = p02 / pr;
                float B11 = (p11 - q) / pr, B12 = p12 / pr, B22 = (p22 - q) / pr;
                float detB = B00 * (B11 * B22 - B12 * B12)
                           - B01 * (B01 * B22 - B12 * B02)
                           + B02 * (B01 * B12 - B11 * B02);
                float r = fminf(1.0f, fmaxf(-1.0f, 0.5f * detB));
                lam = q + 2.0f * pr * cosf(acosf(r) * (1.0f / 3.0f));
            }
            double G00 = p00, G01 = p01, G02 = p02, G11 = p11, G12 = p12, G22 = p22;
            double c2 = G00 + G11 + G22;
            double c1 = G00 * G11 - G01 * G01 + G00 * G22 - G02 * G02 + G11 * G22 - G12 * G12;
            double c0 = G00 * (G11 * G22 - G12 * G12) - G01 * (G01 * G22 - G12 * G02)
                      + G02 * (G01 * G12 - G11 * G02);
            double L = (double)lam;
            #pragma unroll
            for (int it = 0; it < 2; it++) {
                double pv = ((L - c2) * L + c1) * L - c0;
                double dv = (3.0 * L - 2.0 * c2) * L + c1;
                L -= pv / dv;
            }
            inv_sigma = (float)(1.0 / sqrt(L));
        }
        inv_sigma = __shfl(inv_sigma, 0);

        // ---- sample conv: x tile 16x4 ----
        int xl = tl & 15, yl = tl >> 4;
        float4 r[3][4];
        #pragma unroll
        for (int c = 0; c < 3; c++)
            #pragma unroll
            for (int kh = 0; kh < 4; kh++)
                r[c][kh] = *(const float4*)&sx[c * DPLANE + (4 * yl + 3 + kh) * DSTR + 4 * xl + 4];
        float s0 = 0.f, s1 = 0.f, s2 = 0.f;
        #pragma unroll
        for (int c = 0; c < 3; c++)
            #pragma unroll
            for (int kh = 0; kh < 4; kh++) {
                float4 vv = r[c][kh];
                const float* w0 = &sw_g[(0 * 3 + c) * 16 + kh * 4];
                const float* w1 = &sw_g[(1 * 3 + c) * 16 + kh * 4];
                const float* w2 = &sw_g[(2 * 3 + c) * 16 + kh * 4];
                s0 += w0[0] * vv.x + w0[1] * vv.y + w0[2] * vv.z + w0[3] * vv.w;
                s1 += w1[0] * vv.x + w1[1] * vv.y + w1[2] * vv.z + w1[3] * vv.w;
                s2 += w2[0] * vv.x + w2[1] * vv.y + w2[2] * vv.z + w2[3] * vv.w;
            }
        float x0 = fmaf(s0, inv_sigma, sb[0]);
        float x1 = fmaf(s1, inv_sigma, sb[1]);
        float x2 = fmaf(s2, inv_sigma, sb[2]);
        unsigned o = (unsigned)(b * 3) * 65536u + (unsigned)(bandY * 4 + yl) * 256u + tileX * 16 + xl;
        outX[o] = x0; outX[o + 65536u] = x1; outX[o + 131072u] = x2;

        // ---- pool1 via shuffles ----
        int sl = 2 * (tl & 7) + 32 * ((tl >> 3) & 1);
        float q0 = p1b[0], q1 = p1b[1], q2 = p1b[2];
        #pragma unroll
        for (int dy = 0; dy < 2; dy++)
            #pragma unroll
            for (int dx = 0; dx < 2; dx++) {
                int src = sl + dx + 16 * dy;
                float vx0 = __shfl(x0, src);
                float vx1 = __shfl(x1, src);
                float vx2 = __shfl(x2, src);
                int wi = dy * 2 + dx;
                q0 = fmaf(p1w[wi], vx0, q0); q0 = fmaf(p1w[4 + wi],  vx1, q0); q0 = fmaf(p1w[8 + wi],  vx2, q0);
                q1 = fmaf(p1w[12 + wi], vx0, q1); q1 = fmaf(p1w[16 + wi], vx1, q1); q1 = fmaf(p1w[20 + wi], vx2, q1);
                q2 = fmaf(p1w[24 + wi], vx0, q2); q2 = fmaf(p1w[28 + wi], vx1, q2); q2 = fmaf(p1w[32 + wi], vx2, q2);
            }
        if (tl < 16) {
            int px = tl & 7, py = tl >> 3;
            unsigned op = (unsigned)(b * 3) * 16384u + (unsigned)(bandY * 2 + py) * 128u + tileX * 8 + px;
            outP1[op] = q0; outP1[op + 16384u] = q1; outP1[op + 32768u] = q2;
        }

        // ---- pool2 via shuffles ----
        int s2l = 2 * (tl & 3);
        float r0 = p2b[0], r1 = p2b[1], r2 = p2b[2];
        #pragma unroll
        for (int dy = 0; dy < 2; dy++)
            #pragma unroll
            for (int dx = 0; dx < 2; dx++) {
                int src = s2l + dx + 8 * dy;
                float vq0 = __shfl(q0, src);
                float vq1 = __shfl(q1, src);
                float vq2 = __shfl(q2, src);
                int wi = dy * 2 + dx;
                r0 = fmaf(p2w[wi], vq0, r0); r0 = fmaf(p2w[4 + wi],  vq1, r0); r0 = fmaf(p2w[8 + wi],  vq2, r0);
                r1 = fmaf(p2w[12 + wi], vq0, r1); r1 = fmaf(p2w[16 + wi], vq1, r1); r1 = fmaf(p2w[20 + wi], vq2, r1);
                r2 = fmaf(p2w[24 + wi], vq0, r2); r2 = fmaf(p2w[28 + wi], vq1, r2); r2 = fmaf(p2w[32 + wi], vq2, r2);
            }
        if (tl < 4) {
            unsigned op = (unsigned)(b * 3) * 4096u + (unsigned)bandY * 64u + tileX * 4 + tl;
            outP2[op] = r0; outP2[op + 4096u] = r1; outP2[op + 8192u] = r2;
        }
    }
}

// ---------------------------------------------------------------------------
// K1: fused ctx L2+L3 (unchanged from R6).
// ---------------------------------------------------------------------------
__global__ __launch_bounds__(256) void k_fused23(
    const float* __restrict__ h1, float* __restrict__ outF1, float* __restrict__ outF2,
    const float* __restrict__ ctxw, const float* __restrict__ ctxb,
    const float* __restrict__ bng, const float* __restrict__ bnb)
{
    __shared__ float sx[3 * SXCH];
    __shared__ float sm[3 * H0CH];

    int t = threadIdx.x, bid = blockIdx.x;
    int tileX = bid & 3, bandY = (bid >> 2) & 15, b = bid >> 6;

    int gr0 = bandY * 16 - 3;
    int gc0 = tileX * 64 - 4;
    #pragma unroll
    for (int c = 0; c < 3; c++)
        stage19(h1 + (size_t)(b * 3 + c) * 65536, &sx[c * SXCH], gr0, gc0, 256, t);
    __syncthreads();

    {
        const float* w2c = ctxw + 162;
        float inv2[3], bb2[3];
        #pragma unroll
        for (int c = 0; c < 3; c++) { inv2[c] = bng[6 + c] / sqrtf(1.001f); bb2[c] = bnb[6 + c]; }
        #pragma unroll
        for (int p = 0; p < 2; p++) {
            int idx = t + 256 * p;
            if (idx < 297) {
                int lhy = idx / 33;
                int lhx = idx - 33 * lhy;
                bool oob = (bandY == 0 && lhy == 0) || (tileX == 0 && lhx == 0);
                float a0 = ctxb[6], a1 = ctxb[7], a2 = ctxb[8];
                #pragma unroll
                for (int c = 0; c < 3; c++) {
                    const float* basep = &sx[c * SXCH + 2 * lhy * SXSTR + 2 * lhx];
                    float inv = inv2[c], bb = bb2[c];
                    #pragma unroll
                    for (int kh = 0; kh < 3; kh++) {
                        float2 c0 = *(const float2*)(basep + kh * SXSTR);
                        float2 c1 = *(const float2*)(basep + kh * SXSTR + 2);
                        float t0 = fmaxf(fmaf(inv, c0.y, bb), 0.0f);
                        float t1 = fmaxf(fmaf(inv, c1.x, bb), 0.0f);
                        float t2 = fmaxf(fmaf(inv, c1.y, bb), 0.0f);
                        int wi = c * 9 + kh * 3;
                        a0 = fmaf(w2c[wi], t0, a0); a0 = fmaf(w2c[wi + 1], t1, a0); a0 = fmaf(w2c[wi + 2], t2, a0);
                        a1 = fmaf(w2c[27 + wi], t0, a1); a1 = fmaf(w2c[28 + wi], t1, a1); a1 = fmaf(w2c[29 + wi], t2, a1);
                        a2 = fmaf(w2c[54 + wi], t0, a2); a2 = fmaf(w2c[55 + wi], t1, a2); a2 = fmaf(w2c[56 + wi], t2, a2);
                    }
                }
                int o = lhy * H0STR + lhx;
                if (!oob && lhy >= 1 && lhx >= 1) {
                    unsigned fo = (unsigned)(b * 3) * 16384u
                                + (unsigned)(8 * bandY + lhy - 1) * 128u + 32 * tileX + lhx - 1;
                    outF1[fo] = featf(a0); outF1[fo + 16384u] = featf(a1); outF1[fo + 32768u] = featf(a2);
                }
                if (oob) { a0 = SENT; a1 = SENT; a2 = SENT; }
                sm[o] = a0; sm[H0CH + o] = a1; sm[2 * H0CH + o] = a2;
            }
        }
    }
    __syncthreads();

    if (t < 64) {
        int lx = t & 15, ly = t >> 4;
        const float* w3c = ctxw + 243;
        float a0 = ctxb[9], a1 = ctxb[10], a2 = ctxb[11];
        #pragma unroll
        for (int c = 0; c < 3; c++) {
            float inv = bng[9 + c] / sqrtf(1.001f), bb = bnb[9 + c];
            const float* mb = &sm[c * H0CH + 2 * ly * H0STR + 2 * lx];
            #pragma unroll
            for (int kh = 0; kh < 3; kh++) {
                float2 c0 = *(const float2*)(mb + kh * H0STR);
                float c2v = mb[kh * H0STR + 2];
                float t0 = fmaxf(fmaf(inv, c0.x, bb), 0.0f);
                float t1 = fmaxf(fmaf(inv, c0.y, bb), 0.0f);
                float t2 = fmaxf(fmaf(inv, c2v, bb), 0.0f);
                int wi = c * 9 + kh * 3;
                a0 = fmaf(w3c[wi], t0, a0); a0 = fmaf(w3c[wi + 1], t1, a0); a0 = fmaf(w3c[wi + 2], t2, a0);
                a1 = fmaf(w3c[27 + wi], t0, a1); a1 = fmaf(w3c[28 + wi], t1, a1); a1 = fmaf(w3c[29 + wi], t2, a1);
                a2 = fmaf(w3c[54 + wi], t0, a2); a2 = fmaf(w3c[55 + wi], t1, a2); a2 = fmaf(w3c[56 + wi], t2, a2);
            }
        }
        unsigned o = (unsigned)(b * 3) * 4096u + (unsigned)(bandY * 4 + ly) * 64u + tileX * 16 + lx;
        outF2[o] = featf(a0); outF2[o + 4096u] = featf(a1); outF2[o + 8192u] = featf(a2);
    }
}

// ---------------------------------------------------------------------------
// K2: final select + soft VQ + counts + hists -> per-block partials.
// ---------------------------------------------------------------------------
__device__ __forceinline__ int argmin8(float v, const float* __restrict__ sc) {
    float best = 1e30f; int ki = 0;
    #pragma unroll
    for (int k = 0; k < 8; k++) {
        float df = v - sc[k]; float dk = df * df;
        if (dk < best) { best = dk; ki = k; }
    }
    return ki;
}

__global__ __launch_bounds__(256) void k_final(
    const float* __restrict__ x, const float* __restrict__ f1,
    const float* __restrict__ f2, const float* __restrict__ p1,
    const float* __restrict__ p2, const float* __restrict__ thresh,
    const float* __restrict__ centers, float* __restrict__ out,
    int* __restrict__ partials)
{
    __shared__ int sh[4 * 12];
    int t = threadIdx.x;
    int lane = t & 63;
    int* shW = &sh[12 * (t >> 6)];
    if (lane < 12) shW[lane] = 0;
    float sc[8];
    #pragma unroll
    for (int k = 0; k < 8; k++) sc[k] = centers[k];
    __syncthreads();

    float th1 = thresh[0], th2 = thresh[1];
    int gid = blockIdx.x * 256 + t;
    int xc = gid & 255, y = (gid >> 8) & 255, b = gid >> 16;
    unsigned i2 = (unsigned)(((y >> 1) << 7) + (xc >> 1));
    unsigned i4 = (unsigned)(((y >> 2) << 6) + (xc >> 2));
    bool doM1 = ((y & 1) == 0) && ((xc & 1) == 0);
    bool doM2 = ((y & 3) == 0) && ((xc & 3) == 0);
    int c0n = 0, c1n = 0, c2n = 0;

    #pragma unroll
    for (int c = 0; c < 3; c++) {
        unsigned pc = (unsigned)(b * 3 + c);
        float f1v = f1[pc * 16384u + i2];
        float f2v = f2[pc * 4096u + i4];
        float p1v = p1[pc * 16384u + i2];
        float p2v = p2[pc * 4096u + i4];
        float xv  = x[pc * 65536u + (unsigned)((y << 8) + xc)];
        bool cond2 = f2v < th2;
        bool cond1 = (!cond2) && (f1v < th1);
        bool cond0 = !(cond1 || cond2);
        float xq = cond2 ? p2v : (cond1 ? p1v : xv);

        float d[8]; float dmin = 1e30f;
        #pragma unroll
        for (int k = 0; k < 8; k++) { float df = xq - sc[k]; d[k] = df * df; dmin = fminf(dmin, d[k]); }
        float se = 0.f, sn = 0.f;
        #pragma unroll
        for (int k = 0; k < 8; k++) { float e = __expf(dmin - d[k]); se += e; sn = fmaf(sc[k], e, sn); }
        out[pc * 65536u + (unsigned)((y << 8) + xc)] = sn / se;

        c0n += cond0; c1n += cond1; c2n += cond2;

        if (cond0) atomicAdd(&shW[argmin8(xv, sc)], 1);
        if (doM1 && (f2v >= th2) && (f1v < th1)) atomicAdd(&shW[argmin8(p1v, sc)], 1);
        if (doM2 && cond2) atomicAdd(&shW[argmin8(p2v, sc)], 1);
    }
    #pragma unroll
    for (int off = 32; off > 0; off >>= 1) {
        c0n += __shfl_down(c0n, off);
        c1n += __shfl_down(c1n, off);
        c2n += __shfl_down(c2n, off);
    }
    if (lane == 0) { atomicAdd(&shW[8], c0n); atomicAdd(&shW[9], c1n); atomicAdd(&shW[10], c2n); }
    __syncthreads();
    if (t < 12)
        partials[blockIdx.x * 12 + t] = sh[t] + sh[12 + t] + sh[24 + t] + sh[36 + t];
}

// ---------------------------------------------------------------------------
// K3: reduce partials [2048][12] -> scalars. 1 block, 256 threads.
// ---------------------------------------------------------------------------
__global__ void k_reduce(const int* __restrict__ partials, float* __restrict__ out2) {
    __shared__ int accs[12];
    int t = threadIdx.x;
    if (t < 12) accs[t] = 0;
    __syncthreads();
    int s[12];
    #pragma unroll
    for (int k = 0; k < 12; k++) s[k] = 0;
    for (int r = t; r < 2048; r += 256) {
        const int* row = partials + r * 12;
        #pragma unroll
        for (int k = 0; k < 12; k++) s[k] += row[k];
    }
    #pragma unroll
    for (int k = 0; k < 12; k++) {
        #pragma unroll
        for (int off = 32; off > 0; off >>= 1) s[k] += __shfl_down(s[k], off);
    }
    if ((t & 63) == 0) {
        #pragma unroll
        for (int k = 0; k < 12; k++) if (s[k]) atomicAdd(&accs[k], s[k]);
    }
    __syncthreads();
    if (t == 0) {
        float cnt0 = (float)accs[8], cnt1 = (float)accs[9], cnt2 = (float)accs[10];
        float esti = cnt0 + cnt1 * 0.25f + cnt2 * 0.0625f;
        float cr = (1.0f / 16.0f) * esti / (256.0f * 256.0f * 3.0f * 8.0f);
        float cs[8]; float tot = 0.0f;
        #pragma unroll
        for (int k = 0; k < 8; k++) { cs[k] = (float)accs[k]; tot += cs[k]; }
        float mean = 0.0f;
        #pragma unroll
        for (int k = 0; k < 8; k++) { cs[k] /= tot; mean += cs[k]; }
        mean *= 0.125f;
        float var = 0.0f;
        #pragma unroll
        for (int k = 0; k < 8; k++) { float df = cs[k] - mean; var += df * df; }
        var *= (1.0f / 7.0f);
        out2[0] = cr;
        out2[1] = sqrtf(var);
    }
}

extern "C" void kernel_launch(void* const* d_in, const int* in_sizes, int n_in,
                              void* d_out, int out_size, void* d_ws, size_t ws_size,
                              hipStream_t stream) {
    const float* x_init   = (const float*)d_in[0];
    const float* thresh   = (const float*)d_in[1];
    const float* sample_w = (const float*)d_in[2];
    const float* sample_b = (const float*)d_in[3];
    const float* centers  = (const float*)d_in[4];
    const float* pool1_w  = (const float*)d_in[5];
    const float* pool1_b  = (const float*)d_in[6];
    const float* pool2_w  = (const float*)d_in[7];
    const float* pool2_b  = (const float*)d_in[8];
    const float* ctx_w    = (const float*)d_in[9];
    const float* ctx_b    = (const float*)d_in[10];
    const float* bn_g     = (const float*)d_in[11];
    const float* bn_b     = (const float*)d_in[12];
    float* out = (float*)d_out;

    float* wsf      = (float*)d_ws;
    int*   partials = (int*)wsf;               // [2048][12] ints
    float* bufX     = wsf + 32768;             // [8,3,256,256]
    float* bufH1    = bufX  + 1572864;         // [8,3,256,256]
    float* bufP1    = bufH1 + 1572864;         // [8,3,128,128]
    float* bufP2    = bufP1 + 393216;          // [8,3,64,64]
    float* bufF1    = bufP2 + 98304;           // [8,3,128,128]
    float* bufF2    = bufF1 + 393216;          // [8,3,64,64]

    k_fused01<<<8192, 256, 0, stream>>>(x_init, sample_w, sample_b,
                                        ctx_w, ctx_b, bn_g, bn_b,
                                        pool1_w, pool1_b, pool2_w, pool2_b,
                                        bufX, bufH1, bufP1, bufP2);
    k_fused23<<<512, 256, 0, stream>>>(bufH1, bufF1, bufF2,
                                       ctx_w, ctx_b, bn_g, bn_b);
    k_final<<<2048, 256, 0, stream>>>(bufX, bufF1, bufF2, bufP1, bufP2,
                                      thresh, centers, out, partials);
    k_reduce<<<1, 256, 0, stream>>>(partials, out + 1572864);
}